// Round 2
// baseline (12069.324 us; speedup 1.0000x reference)
//
#include <hip/hip_runtime.h>
#include <hip/hip_bf16.h>

#define Nn 8192
#define Ne 131072
#define Cc 256
#define Bb 64

typedef __hip_bfloat16 bf16;

// ---------------- block-wide reduction (256 threads, 2 values) ----------------
__device__ __forceinline__ void block_reduce_2(float& s1, float& s2, float* sm){
#pragma unroll
  for (int off = 32; off > 0; off >>= 1){
    s1 += __shfl_down(s1, off, 64);
    s2 += __shfl_down(s2, off, 64);
  }
  int lane = threadIdx.x & 63;
  int wid  = threadIdx.x >> 6;
  if (lane == 0){ sm[wid] = s1; sm[4 + wid] = s2; }
  __syncthreads();
  s1 = sm[0] + sm[1] + sm[2] + sm[3];
  s2 = sm[4] + sm[5] + sm[6] + sm[7];
}

// ---------------- generic tiled GEMM ----------------
// C[M x Nout] = act( A @ W + bias ) (+ res).  A = up to 3 concatenated
// segments, each with ptr / row-gather idx / width K / leading dim / dtype
// (0=f32, 1=bf16). rbfMode: A0 = d[] (E floats), A(i,k)=exp(-GAMMA*(d-c_k)^2).
// aScale/aShift: per-k affine on A (folds column BN). outDt: 0=f32, 1=bf16.
__global__ __launch_bounds__(256) void gemm_k(
  const void* __restrict__ A0, const int* __restrict__ idx0, int K0, int ld0, int dt0,
  const void* __restrict__ A1, const int* __restrict__ idx1, int K1, int ld1, int dt1,
  const void* __restrict__ A2, const int* __restrict__ idx2, int K2, int ld2, int dt2,
  long M, int Ktot, int Nout,
  const float* __restrict__ W, const float* __restrict__ bias,
  const float* __restrict__ res, int ldRes,
  const float* __restrict__ aScale, const float* __restrict__ aShift,
  void* __restrict__ Cout, int outDt, int actMode, int rbfMode)
{
  __shared__ __align__(16) float As[16][64];
  __shared__ __align__(16) float Bs[16][128];

  int t = threadIdx.x;
  long m0 = (long)blockIdx.x * 64;
  int  n0 = blockIdx.y * 128;

  float acc[4][8];
#pragma unroll
  for (int i = 0; i < 4; i++)
#pragma unroll
    for (int j = 0; j < 8; j++) acc[i][j] = 0.f;

  int tm = t >> 4;        // 0..15 -> rows tm*4..tm*4+3
  int tn = t & 15;        // 0..15 -> cols tn*4.. / 64+tn*4..
  int mA  = t & 63;       // staging row
  int kgA = t >> 6;       // staging k-group 0..3

  long rowA = m0 + mA;
  bool rv = rowA < M;
  long r0 = 0, r1 = 0, r2 = 0;
  float dval = 0.f;
  if (rv){
    if (rbfMode) dval = ((const float*)A0)[rowA];
    else {
      r0 = idx0 ? (long)idx0[rowA] : rowA;
      if (A1) r1 = idx1 ? (long)idx1[rowA] : rowA;
      if (A2) r2 = idx2 ? (long)idx2[rowA] : rowA;
    }
  }

  for (int k0 = 0; k0 < Ktot; k0 += 16){
    // ---- stage A (transposed): As[kl][m] ----
#pragma unroll
    for (int it = 0; it < 4; it++){
      int kl = kgA + it * 4;
      int k  = k0 + kl;
      float v = 0.f;
      if (rv){
        if (rbfMode){
          float cen = -6.0f + (float)k * (6.0f / 255.0f);
          float df  = dval - cen;
          v = __expf(-42.5f * df * df);
        } else if (k < Ktot){
          const void* S; long r; int ld, kb, dt;
          if (k < K0)             { S = A0; r = r0; ld = ld0; kb = k; dt = dt0; }
          else if (k < K0 + K1)   { S = A1; r = r1; ld = ld1; kb = k - K0; dt = dt1; }
          else                    { S = A2; r = r2; ld = ld2; kb = k - K0 - K1; dt = dt2; }
          v = dt ? __bfloat162float(((const bf16*)S)[r * (long)ld + kb])
                 : ((const float*)S)[r * (long)ld + kb];
          if (aScale) v = v * aScale[k] + aShift[k];
        }
      }
      As[kl][mA] = v;
    }
    // ---- stage B: Bs[kl][n] ----
#pragma unroll
    for (int it = 0; it < 8; it++){
      int idx = t + it * 256;
      int kl = idx >> 7;
      int n  = idx & 127;
      int k  = k0 + kl;
      Bs[kl][n] = (k < Ktot) ? W[(long)k * Nout + n0 + n] : 0.f;
    }
    __syncthreads();
#pragma unroll
    for (int kk = 0; kk < 16; kk++){
      float4 a  = *(const float4*)&As[kk][tm * 4];
      float4 b0 = *(const float4*)&Bs[kk][tn * 4];
      float4 b1 = *(const float4*)&Bs[kk][64 + tn * 4];
      float av[4] = {a.x, a.y, a.z, a.w};
      float bv[8] = {b0.x, b0.y, b0.z, b0.w, b1.x, b1.y, b1.z, b1.w};
#pragma unroll
      for (int i = 0; i < 4; i++)
#pragma unroll
        for (int j = 0; j < 8; j++)
          acc[i][j] = __builtin_fmaf(av[i], bv[j], acc[i][j]);
    }
    __syncthreads();
  }

  // ---- epilogue ----
#pragma unroll
  for (int i = 0; i < 4; i++){
    long m = m0 + tm * 4 + i;
    if (m >= M) continue;
#pragma unroll
    for (int h = 0; h < 2; h++){
      int nb = n0 + h * 64 + tn * 4;
      float po[4];
#pragma unroll
      for (int j = 0; j < 4; j++){
        float v = acc[i][h * 4 + j];
        if (bias) v += bias[nb + j];
        if (actMode == 1) v = v / (1.0f + __expf(-v));   // SiLU
        if (res) v += res[m * (long)ldRes + nb + j];
        po[j] = v;
      }
      if (outDt){
        __align__(8) bf16 tb[4];
#pragma unroll
        for (int j = 0; j < 4; j++) tb[j] = __float2bfloat16(po[j]);
        *(short4*)((bf16*)Cout + m * (long)Nout + nb) = *(short4*)tb;
      } else {
        float4 ov = {po[0], po[1], po[2], po[3]};
        *(float4*)((float*)Cout + m * (long)Nout + nb) = ov;
      }
    }
  }
}

// ---------------- utility: zero / copy ----------------
__global__ __launch_bounds__(256) void zero_k(float* __restrict__ p, long n){
  long i = (long)blockIdx.x * 256 + threadIdx.x;
  long stride = (long)gridDim.x * 256;
  for (; i < n; i += stride) p[i] = 0.f;
}
__global__ __launch_bounds__(256) void copy_k(float* __restrict__ d,
                                              const float* __restrict__ s, long n){
  long i = (long)blockIdx.x * 256 + threadIdx.x;
  long stride = (long)gridDim.x * 256;
  for (; i < n; i += stride) d[i] = s[i];
}

// ---------------- fused bias: bf[n] = b0[n] + sum_k be[k]*W3[k*256+n] ----------------
__global__ __launch_bounds__(256) void fuse_bias_k(
  const float* __restrict__ W3, const float* __restrict__ be,
  const float* __restrict__ b0, float* __restrict__ bf)
{
  int n = threadIdx.x;
  float s = b0[n];
  for (int k = 0; k < Cc; k++) s += be[k] * W3[k * Cc + n];
  bf[n] = s;
}

// ---------------- d = -1/||edge_attr|| ----------------
__global__ __launch_bounds__(256) void d_k(const float* __restrict__ ea,
                                           float* __restrict__ d, int E)
{
  int i = blockIdx.x * 256 + threadIdx.x;
  if (i < E){
    float a = ea[i * 3 + 0], b = ea[i * 3 + 1], c = ea[i * 3 + 2];
    d[i] = -rsqrtf(a * a + b * b + c * c);
  }
}

// ---------------- msg *= sigmoid(LN(q[dst]*key_e*scale)) ----------------
__global__ __launch_bounds__(256) void ln_gate_k(
  bf16* __restrict__ msg, const bf16* __restrict__ keye,
  const float* __restrict__ q, const int* __restrict__ dst,
  const float* __restrict__ g, const float* __restrict__ b)
{
  __shared__ float sm[8];
  long row = blockIdx.x;
  int c = threadIdx.x;
  long dr = dst[row];
  float a = __bfloat162float(keye[row * Cc + c]) * q[dr * Cc + c] * 0.0625f;
  float s1 = a, s2 = a * a;
  block_reduce_2(s1, s2, sm);
  float m   = s1 * (1.0f / Cc);
  float var = s2 * (1.0f / Cc) - m * m;
  float ln  = (a - m) * rsqrtf(var + 1e-5f) * g[c] + b[c];
  float sg  = 1.0f / (1.0f + __expf(-ln));
  float mv  = __bfloat162float(msg[row * Cc + c]) * sg;
  msg[row * Cc + c] = __float2bfloat16(mv);
}

// ---------------- agg[dst] += LN(row) ----------------
__global__ __launch_bounds__(256) void ln_scatter_k(
  const bf16* __restrict__ src, const int* __restrict__ dst,
  const float* __restrict__ g, const float* __restrict__ b,
  float* __restrict__ agg)
{
  __shared__ float sm[8];
  long row = blockIdx.x;
  int c = threadIdx.x;
  float v = __bfloat162float(src[row * Cc + c]);
  float s1 = v, s2 = v * v;
  block_reduce_2(s1, s2, sm);
  float m   = s1 * (1.0f / Cc);
  float var = s2 * (1.0f / Cc) - m * m;
  float ln  = (v - m) * rsqrtf(var + 1e-5f) * g[c] + b[c];
  long dr = dst[row];
  atomicAdd(&agg[dr * Cc + c], ln);
}

// ---------------- per-column sums for BatchNorm ----------------
__global__ __launch_bounds__(256) void bn_stats_k(
  const float* __restrict__ X, int rows, float* __restrict__ sums)
{
  int c  = threadIdx.x;
  int r0 = blockIdx.x * 128;
  int re = r0 + 128; if (re > rows) re = rows;
  float s1 = 0.f, s2 = 0.f;
  for (int r = r0; r < re; r++){
    float v = X[(long)r * Cc + c];
    s1 += v; s2 += v * v;
  }
  atomicAdd(&sums[c],      s1);
  atomicAdd(&sums[Cc + c], s2);
}

// ---------------- x = softplus(x + BN(agg)) ----------------
__global__ __launch_bounds__(256) void bn_apply_softplus_k(
  float* __restrict__ x, const float* __restrict__ agg,
  const float* __restrict__ sums,
  const float* __restrict__ g, const float* __restrict__ b)
{
  long r = blockIdx.x;
  int c = threadIdx.x;
  float m    = sums[c] * (1.0f / Nn);
  float var  = sums[Cc + c] * (1.0f / Nn) - m * m;
  float rstd = rsqrtf(var + 1e-5f);
  float bn = (agg[r * Cc + c] - m) * rstd * g[c] + b[c];
  float v  = x[r * Cc + c] + bn;
  float sp = (v > 0.f) ? v + log1pf(__expf(-v)) : log1pf(__expf(v));
  x[r * Cc + c] = sp;
}

// ---------------- BN -> per-column scale/shift ----------------
__global__ __launch_bounds__(256) void bn_st_k(
  const float* __restrict__ sums, const float* __restrict__ g,
  const float* __restrict__ b, float* __restrict__ S, float* __restrict__ T)
{
  int c = threadIdx.x;
  float m    = sums[c] * (1.0f / Nn);
  float var  = sums[Cc + c] * (1.0f / Nn) - m * m;
  float rstd = rsqrtf(var + 1e-5f);
  S[c] = g[c] * rstd;
  T[c] = b[c] - m * rstd * g[c];
}

// ---------------- p += x ----------------
__global__ __launch_bounds__(256) void add_k(float* __restrict__ p,
                                             const float* __restrict__ x)
{
  long i = (long)blockIdx.x * 256 + threadIdx.x;
  p[i] += x[i];
}

// ---------------- u = x1 * gelu_exact(a2[:, C:]) ----------------
__global__ __launch_bounds__(256) void mulgelu_k(
  float* __restrict__ u, const float* __restrict__ x1,
  const float* __restrict__ a2)
{
  long r = blockIdx.x;
  int c = threadIdx.x;
  float xg = a2[r * 512 + 256 + c];
  float ge = 0.5f * xg * (1.0f + erff(xg * 0.70710678118654752f));
  u[r * Cc + c] = x1[r * Cc + c] * ge;
}

// ---------------- pooling ----------------
__global__ __launch_bounds__(256) void pool_k(
  const float* __restrict__ x, const int* __restrict__ batch,
  float* __restrict__ pooled, float* __restrict__ counts)
{
  long r = blockIdx.x;
  int c = threadIdx.x;
  long b = batch[r];
  atomicAdd(&pooled[b * Cc + c], x[r * Cc + c]);
  if (c == 0) atomicAdd(&counts[b], 1.0f);
}

__global__ __launch_bounds__(256) void pooldiv_k(
  float* __restrict__ pooled, const float* __restrict__ counts)
{
  int b = blockIdx.x;
  int c = threadIdx.x;
  float cnt = counts[b];
  if (cnt < 1.f) cnt = 1.f;
  pooled[b * Cc + c] /= cnt;
}

// ---------------- out[b] = cf[b] . out_W + out_b ----------------
__global__ __launch_bounds__(256) void out_k(
  const float* __restrict__ cf, const float* __restrict__ ow,
  const float* __restrict__ ob, float* __restrict__ out)
{
  __shared__ float sm[8];
  int b = blockIdx.x;
  int c = threadIdx.x;
  float v = cf[(long)b * Cc + c] * ow[c];
  float dummy = 0.f;
  block_reduce_2(v, dummy, sm);
  if (c == 0) out[b] = v + ob[0];
}

// ---------------- host ----------------
static inline void launch_gemm(hipStream_t st,
  const void* A0, const int* i0, int K0, int ld0, int dt0,
  const void* A1, const int* i1, int dt1,
  const void* A2, const int* i2, int dt2,
  long M, int Nout, const float* W, const float* bias,
  const float* res, int ldRes, const float* aS, const float* aT,
  void* Cout, int outDt, int act, int rbf)
{
  int K1 = A1 ? 256 : 0, K2 = A2 ? 256 : 0;
  dim3 grid((unsigned)((M + 63) / 64), (unsigned)(Nout / 128));
  gemm_k<<<grid, dim3(256), 0, st>>>(
    A0, i0, K0, ld0, dt0, A1, i1, K1, 256, dt1, A2, i2, K2, 256, dt2,
    M, K0 + K1 + K2, Nout, W, bias, res, ldRes, aS, aT, Cout, outDt, act, rbf);
}

extern "C" void kernel_launch(void* const* d_in, const int* in_sizes, int n_in,
                              void* d_out, int out_size, void* d_ws, size_t ws_size,
                              hipStream_t stream)
{
  (void)in_sizes; (void)n_in; (void)out_size; (void)ws_size;

  const float* node       = (const float*)d_in[0];
  const int*   edge_index = (const int*)  d_in[1];
  const float* edge_attr  = (const float*)d_in[2];
  const float* pdd        = (const float*)d_in[3];
  const int*   batch      = (const int*)  d_in[4];
  const float* atom_W1 = (const float*)d_in[5];
  const float* atom_b1 = (const float*)d_in[6];
  const float* atom_W2 = (const float*)d_in[7];
  const float* atom_b2 = (const float*)d_in[8];
  const float* edge_W  = (const float*)d_in[9];
  const float* edge_b  = (const float*)d_in[10];
  const float* pdd_W   = (const float*)d_in[11];
  const float* pdd_b   = (const float*)d_in[12];
  const float* conv_Wq = (const float*)d_in[13];
  const float* conv_bq = (const float*)d_in[14];
  const float* conv_Wk = (const float*)d_in[15];
  const float* conv_bk = (const float*)d_in[16];
  const float* conv_Wv = (const float*)d_in[17];
  const float* conv_bv = (const float*)d_in[18];
  const float* conv_We = (const float*)d_in[19];
  const float* conv_be = (const float*)d_in[20];
  const float* conv_Wku = (const float*)d_in[21];
  const float* conv_bku = (const float*)d_in[22];
  const float* conv_Wmu = (const float*)d_in[23];
  const float* conv_bmu = (const float*)d_in[24];
  const float* conv_Wm  = (const float*)d_in[25];
  const float* conv_bm  = (const float*)d_in[26];
  const float* ln_m_g = (const float*)d_in[27];
  const float* ln_m_b = (const float*)d_in[28];
  const float* ln_a_g = (const float*)d_in[29];
  const float* ln_a_b = (const float*)d_in[30];
  const float* bn_g   = (const float*)d_in[31];
  const float* bn_b   = (const float*)d_in[32];
  const float* pddc_W1 = (const float*)d_in[33];
  const float* pddc_b1 = (const float*)d_in[34];
  const float* pddc_W2 = (const float*)d_in[35];
  const float* pddc_b2 = (const float*)d_in[36];
  const float* pddc_W3 = (const float*)d_in[37];
  const float* pddc_b3 = (const float*)d_in[38];
  const float* pddc_bn_g = (const float*)d_in[39];
  const float* pddc_bn_b = (const float*)d_in[40];
  const float* fc_W  = (const float*)d_in[41];
  const float* fc_b  = (const float*)d_in[42];
  const float* out_W = (const float*)d_in[43];
  const float* out_b = (const float*)d_in[44];

  const int* src = edge_index;        // edge_index[0]
  const int* dst = edge_index + Ne;   // edge_index[1]

  // ---- workspace carve-up (~245 MB total) ----
  char* ws = (char*)d_ws;
  size_t off = 0;
  auto alloc = [&](size_t nbytes) -> char* {
    char* ptr = ws + off;
    off += (nbytes + 255) & ~(size_t)255;
    return ptr;
  };
  bf16*  e_in = (bf16*) alloc((size_t)Ne * Cc * 2);  // 64 MB, persistent
  bf16*  bufB = (bf16*) alloc((size_t)Ne * Cc * 2);  // key_e / msg2 (+pddc f32 scratch)
  bf16*  bufC = (bf16*) alloc((size_t)Ne * Cc * 2);  // msg (+pddc a2 f32 scratch)
  float* x    = (float*)alloc((size_t)Nn * Cc * 4);
  float* p    = (float*)alloc((size_t)Nn * Cc * 4);
  float* q    = (float*)alloc((size_t)Nn * Cc * 4);
  float* kk_  = (float*)alloc((size_t)Nn * Cc * 4);
  float* vv_  = (float*)alloc((size_t)Nn * Cc * 4);
  float* agg  = (float*)alloc((size_t)Nn * Cc * 4);
  float* dArr   = (float*)alloc((size_t)Ne * 4);
  float* Wf_ku  = (float*)alloc((size_t)3 * 768 * Cc * 4);  // fused [Wku12; We@Wku3]
  float* Wf_mu  = (float*)alloc((size_t)3 * 768 * Cc * 4);
  float* bf_ku  = (float*)alloc((size_t)3 * Cc * 4);
  float* bf_mu  = (float*)alloc((size_t)3 * Cc * 4);
  float* pooled = (float*)alloc((size_t)Bb * Cc * 4);
  float* counts = (float*)alloc((size_t)Bb * 4);
  float* cf     = (float*)alloc((size_t)Bb * Cc * 4);
  float* bnsum  = (float*)alloc(2 * Cc * 4);
  float* bnS    = (float*)alloc(Cc * 4);
  float* bnT    = (float*)alloc(Cc * 4);

  // pddc fp32 scratch aliases the (then-free) edge buffers
  float* a2buf = (float*)bufC;                    // N x 512
  float* x1buf = (float*)bufB;                    // N x 256
  float* ubuf  = x1buf + (size_t)Nn * Cc;         // N x 256

  // ---- precompute ----
  d_k<<<dim3((Ne + 255) / 256), dim3(256), 0, stream>>>(edge_attr, dArr, Ne);

  // fused weights: Wf = [W_kv-rows(0:512) ; We @ W-rows(512:768)], fused bias
  for (int i = 0; i < 3; i++){
    const float* We_i = conv_We + (size_t)i * Cc * Cc;
    const float* be_i = conv_be + i * Cc;
    const float* Wku_i = conv_Wku + (size_t)i * 768 * Cc;
    const float* Wmu_i = conv_Wmu + (size_t)i * 768 * Cc;
    float* Fku = Wf_ku + (size_t)i * 768 * Cc;
    float* Fmu = Wf_mu + (size_t)i * 768 * Cc;
    copy_k<<<dim3(512), dim3(256), 0, stream>>>(Fku, Wku_i, (long)512 * Cc);
    copy_k<<<dim3(512), dim3(256), 0, stream>>>(Fmu, Wmu_i, (long)512 * Cc);
    launch_gemm(stream, We_i, nullptr, 256, 256, 0, nullptr, nullptr, 0,
                nullptr, nullptr, 0, 256, Cc, Wku_i + (size_t)512 * Cc, nullptr,
                nullptr, 0, nullptr, nullptr, Fku + (size_t)512 * Cc, 0, 0, 0);
    launch_gemm(stream, We_i, nullptr, 256, 256, 0, nullptr, nullptr, 0,
                nullptr, nullptr, 0, 256, Cc, Wmu_i + (size_t)512 * Cc, nullptr,
                nullptr, 0, nullptr, nullptr, Fmu + (size_t)512 * Cc, 0, 0, 0);
    fuse_bias_k<<<dim3(1), dim3(256), 0, stream>>>(Wku_i + (size_t)512 * Cc, be_i,
                conv_bku + i * Cc, bf_ku + i * Cc);
    fuse_bias_k<<<dim3(1), dim3(256), 0, stream>>>(Wmu_i + (size_t)512 * Cc, be_i,
                conv_bmu + i * Cc, bf_mu + i * Cc);
  }

  // x = silu(node @ W1 + b1) @ W2 + b2   (hidden staged in q)
  launch_gemm(stream, node, nullptr, 92, 92, 0, nullptr, nullptr, 0, nullptr, nullptr, 0,
              Nn, Cc, atom_W1, atom_b1, nullptr, 0, nullptr, nullptr, q, 0, 1, 0);
  launch_gemm(stream, q, nullptr, 256, 256, 0, nullptr, nullptr, 0, nullptr, nullptr, 0,
              Nn, Cc, atom_W2, atom_b2, nullptr, 0, nullptr, nullptr, x, 0, 0, 0);
  // e_in = silu(rbf(d) @ edge_W + edge_b)  -> bf16
  launch_gemm(stream, dArr, nullptr, 256, 0, 0, nullptr, nullptr, 0, nullptr, nullptr, 0,
              Ne, Cc, edge_W, edge_b, nullptr, 0, nullptr, nullptr, e_in, 1, 1, 1);
  // p = pdd @ pdd_W + pdd_b
  launch_gemm(stream, pdd, nullptr, 51, 51, 0, nullptr, nullptr, 0, nullptr, nullptr, 0,
              Nn, Cc, pdd_W, pdd_b, nullptr, 0, nullptr, nullptr, p, 0, 0, 0);

  for (int i = 0; i < 3; i++){
    const float* Wq = conv_Wq + (size_t)i * Cc * Cc;
    const float* Wk = conv_Wk + (size_t)i * Cc * Cc;
    const float* Wv = conv_Wv + (size_t)i * Cc * Cc;
    const float* Wm = conv_Wm + (size_t)i * Cc * Cc;

    launch_gemm(stream, x, nullptr, 256, 256, 0, nullptr, nullptr, 0, nullptr, nullptr, 0,
                Nn, Cc, Wq, conv_bq + i * Cc, nullptr, 0, nullptr, nullptr, q, 0, 0, 0);
    launch_gemm(stream, x, nullptr, 256, 256, 0, nullptr, nullptr, 0, nullptr, nullptr, 0,
                Nn, Cc, Wk, conv_bk + i * Cc, nullptr, 0, nullptr, nullptr, kk_, 0, 0, 0);
    launch_gemm(stream, x, nullptr, 256, 256, 0, nullptr, nullptr, 0, nullptr, nullptr, 0,
                Nn, Cc, Wv, conv_bv + i * Cc, nullptr, 0, nullptr, nullptr, vv_, 0, 0, 0);
    // key_e = [k[dst], k[src], e_in] @ Wf_ku + bf_ku   -> bufB bf16
    launch_gemm(stream, kk_, dst, 256, 256, 0, kk_, src, 0, e_in, nullptr, 1,
                Ne, Cc, Wf_ku + (size_t)i * 768 * Cc, bf_ku + i * Cc,
                nullptr, 0, nullptr, nullptr, bufB, 1, 0, 0);
    // msg = [v[dst], v[src], e_in] @ Wf_mu + bf_mu     -> bufC bf16
    launch_gemm(stream, vv_, dst, 256, 256, 0, vv_, src, 0, e_in, nullptr, 1,
                Ne, Cc, Wf_mu + (size_t)i * 768 * Cc, bf_mu + i * Cc,
                nullptr, 0, nullptr, nullptr, bufC, 1, 0, 0);
    // msg *= sigmoid(LN(q[dst]*key_e*scale))
    ln_gate_k<<<dim3(Ne), dim3(256), 0, stream>>>(bufC, bufB, q, dst,
                ln_a_g + i * Cc, ln_a_b + i * Cc);
    // msg2 = msg @ Wm + bm   -> bufB bf16
    launch_gemm(stream, bufC, nullptr, 256, 256, 1, nullptr, nullptr, 0, nullptr, nullptr, 0,
                Ne, Cc, Wm, conv_bm + i * Cc, nullptr, 0, nullptr, nullptr, bufB, 1, 0, 0);
    // agg = segment_sum(LN(msg2), dst)
    zero_k<<<dim3(1024), dim3(256), 0, stream>>>(agg, (long)Nn * Cc);
    ln_scatter_k<<<dim3(Ne), dim3(256), 0, stream>>>(bufB, dst,
                ln_m_g + i * Cc, ln_m_b + i * Cc, agg);
    // x = softplus(x + BN(agg))
    zero_k<<<dim3(2), dim3(256), 0, stream>>>(bnsum, 2 * Cc);
    bn_stats_k<<<dim3(Nn / 128), dim3(256), 0, stream>>>(agg, Nn, bnsum);
    bn_apply_softplus_k<<<dim3(Nn), dim3(256), 0, stream>>>(x, agg, bnsum,
                bn_g + i * Cc, bn_b + i * Cc);

    if (i < 2){
      int j = i;
      // adj = p + x
      add_k<<<dim3(Nn * Cc / 256), dim3(256), 0, stream>>>(p, x);
      // BN(adj) folded into GEMM A-affine
      zero_k<<<dim3(2), dim3(256), 0, stream>>>(bnsum, 2 * Cc);
      bn_stats_k<<<dim3(Nn / 128), dim3(256), 0, stream>>>(p, Nn, bnsum);
      bn_st_k<<<dim3(1), dim3(256), 0, stream>>>(bnsum,
                pddc_bn_g + j * Cc, pddc_bn_b + j * Cc, bnS, bnT);
      // a2 = BN(adj) @ W1 + b1   (N x 512)
      launch_gemm(stream, p, nullptr, 256, 256, 0, nullptr, nullptr, 0, nullptr, nullptr, 0,
                  Nn, 512, pddc_W1 + (size_t)j * Cc * 512, pddc_b1 + j * 512,
                  nullptr, 0, bnS, bnT, a2buf, 0, 0, 0);
      // x1 = a2[:, :C] @ W2 + b2
      launch_gemm(stream, a2buf, nullptr, 256, 512, 0, nullptr, nullptr, 0, nullptr, nullptr, 0,
                  Nn, Cc, pddc_W2 + (size_t)j * Cc * Cc, pddc_b2 + j * Cc,
                  nullptr, 0, nullptr, nullptr, x1buf, 0, 0, 0);
      // u = x1 * gelu(a2[:, C:])
      mulgelu_k<<<dim3(Nn), dim3(256), 0, stream>>>(ubuf, x1buf, a2buf);
      // x = u @ W3 + b3 + x
      launch_gemm(stream, ubuf, nullptr, 256, 256, 0, nullptr, nullptr, 0, nullptr, nullptr, 0,
                  Nn, Cc, pddc_W3 + (size_t)j * Cc * Cc, pddc_b3 + j * Cc,
                  x, Cc, nullptr, nullptr, x, 0, 0, 0);
    }
  }

  // ---- pooling + head ----
  zero_k<<<dim3(64), dim3(256), 0, stream>>>(pooled, (long)Bb * Cc);
  zero_k<<<dim3(1), dim3(256), 0, stream>>>(counts, Bb);
  pool_k<<<dim3(Nn), dim3(256), 0, stream>>>(x, batch, pooled, counts);
  pooldiv_k<<<dim3(Bb), dim3(256), 0, stream>>>(pooled, counts);
  // cf = pooled + silu(pooled @ fc_W + fc_b)
  launch_gemm(stream, pooled, nullptr, 256, 256, 0, nullptr, nullptr, 0, nullptr, nullptr, 0,
              Bb, Cc, fc_W, fc_b, pooled, Cc, nullptr, nullptr, cf, 0, 1, 0);
  out_k<<<dim3(Bb), dim3(256), 0, stream>>>(cf, out_W, out_b, (float*)d_out);
}

// Round 3
// 4981.734 us; speedup vs baseline: 2.4227x; 2.4227x over previous
//
#include <hip/hip_runtime.h>
#include <hip/hip_bf16.h>

#define Nn 8192
#define Ne 131072
#define Cc 256
#define Bb 64

typedef __hip_bfloat16 bf16;
typedef __attribute__((ext_vector_type(8))) short bf16x8;
typedef __attribute__((ext_vector_type(4))) float f32x4;

__device__ __forceinline__ float b2f(unsigned short s){
  return __uint_as_float(((unsigned)s) << 16);
}
__device__ __forceinline__ unsigned short f2b(float v){
  bf16 h = __float2bfloat16(v);
  return *(unsigned short*)&h;
}

// ---------------- block-wide reduction (256 threads, 2 values) ----------------
__device__ __forceinline__ void block_reduce_2(float& s1, float& s2, float* sm){
#pragma unroll
  for (int off = 32; off > 0; off >>= 1){
    s1 += __shfl_down(s1, off, 64);
    s2 += __shfl_down(s2, off, 64);
  }
  int lane = threadIdx.x & 63;
  int wid  = threadIdx.x >> 6;
  if (lane == 0){ sm[wid] = s1; sm[4 + wid] = s2; }
  __syncthreads();
  s1 = sm[0] + sm[1] + sm[2] + sm[3];
  s2 = sm[4] + sm[5] + sm[6] + sm[7];
}

// ================= MFMA bf16 GEMM, N=256, K = nseg*256 =================
// BM=64, BN=256; 4 waves, each 64 rows x 64 cols, 16x16x32 mfma, fp32 acc.
// A segments: bf16, row width 256, optional row-gather idx.
// Bpack layout: element B[kc*32 + (lane>>4)*8 + j][nt*16 + (lane&15)] at
//   Bpack[((kc*16 + nt)*64 + lane)*8 + j]
__global__ __launch_bounds__(256) void mfma_gemm_k(
  const bf16* __restrict__ A0, const int* __restrict__ idx0,
  const bf16* __restrict__ A1, const int* __restrict__ idx1,
  const bf16* __restrict__ A2, const int* __restrict__ idx2,
  int nseg, long M,
  const bf16* __restrict__ Bpack, const float* __restrict__ bias,
  bf16* __restrict__ Cout, int actMode)
{
  int lane = threadIdx.x & 63;
  int wave = threadIdx.x >> 6;
  long m0 = (long)blockIdx.x * 64;
  int row16 = lane & 15;
  int kg    = lane >> 4;

  const bf16* Aseg[3] = {A0, A1, A2};
  const int*  Iseg[3] = {idx0, idx1, idx2};
  const bf16* abase[3][4];
  for (int s = 0; s < nseg; s++){
#pragma unroll
    for (int im = 0; im < 4; im++){
      long r = m0 + im * 16 + row16;
      long g = Iseg[s] ? (long)Iseg[s][r] : r;
      abase[s][im] = Aseg[s] + g * 256 + kg * 8;
    }
  }

  f32x4 acc[4][4];
#pragma unroll
  for (int i = 0; i < 4; i++)
#pragma unroll
    for (int j = 0; j < 4; j++) acc[i][j] = (f32x4){0.f, 0.f, 0.f, 0.f};

  int ntbase = wave * 4;
  for (int s = 0; s < nseg; s++){
    int kcbase = s * 8;
#pragma unroll
    for (int c8 = 0; c8 < 8; c8++){
      bf16x8 afrag[4], bfrag[4];
#pragma unroll
      for (int im = 0; im < 4; im++)
        afrag[im] = *(const bf16x8*)(abase[s][im] + c8 * 32);
      int kc = kcbase + c8;
#pragma unroll
      for (int in = 0; in < 4; in++){
        size_t bidx = ((size_t)(kc * 16 + ntbase + in) * 64 + lane) * 8;
        bfrag[in] = *(const bf16x8*)(Bpack + bidx);
      }
#pragma unroll
      for (int im = 0; im < 4; im++)
#pragma unroll
        for (int in = 0; in < 4; in++)
          acc[im][in] = __builtin_amdgcn_mfma_f32_16x16x32_bf16(
                          afrag[im], bfrag[in], acc[im][in], 0, 0, 0);
    }
  }

  // epilogue: C/D layout col=lane&15, row=(lane>>4)*4+reg
  int colq = lane & 15;
  int quad = lane >> 4;
#pragma unroll
  for (int im = 0; im < 4; im++){
#pragma unroll
    for (int in = 0; in < 4; in++){
      int col = wave * 64 + in * 16 + colq;
      float bv = bias ? bias[col] : 0.f;
#pragma unroll
      for (int r = 0; r < 4; r++){
        long m = m0 + im * 16 + quad * 4 + r;
        float v = acc[im][in][r] + bv;
        if (actMode == 1) v = v / (1.f + __expf(-v));
        Cout[m * 256 + col] = __float2bfloat16(v);
      }
    }
  }
}

// ---------------- pack fp32 W[K][256] -> bf16 fragment layout ----------------
__global__ __launch_bounds__(256) void pack_b_k(
  const float* __restrict__ W, bf16* __restrict__ out, int K)
{
  long p = (long)blockIdx.x * 256 + threadIdx.x;
  if (p >= (long)K * 256) return;
  int j    = p & 7;
  int lane = (p >> 3) & 63;
  int nt   = (p >> 9) & 15;
  int kc   = p >> 13;
  int k = kc * 32 + (lane >> 4) * 8 + j;
  int n = nt * 16 + (lane & 15);
  out[p] = __float2bfloat16(W[(long)k * 256 + n]);
}

// ---------------- rbf matrix (Ne x 256) bf16 ----------------
__global__ __launch_bounds__(256) void rbf_k(
  const float* __restrict__ d, bf16* __restrict__ out)
{
  long id = (long)blockIdx.x * 256 + threadIdx.x;
  long m = id >> 8;
  int  k = id & 255;
  float cen = -6.0f + (float)k * (6.0f / 255.0f);
  float df  = d[m] - cen;
  out[id] = __float2bfloat16(__expf(-42.5f * df * df));
}

// ================= generic fp32 tiled GEMM (node-sized ops) =================
__global__ __launch_bounds__(256) void gemm_k(
  const void* __restrict__ A0, const int* __restrict__ idx0, int K0, int ld0, int dt0,
  long M, int Ktot, int Nout,
  const float* __restrict__ W, const float* __restrict__ bias,
  const float* __restrict__ res, int ldRes,
  const float* __restrict__ aScale, const float* __restrict__ aShift,
  void* __restrict__ Cout, int outDt, int actMode)
{
  __shared__ __align__(16) float As[16][64];
  __shared__ __align__(16) float Bs[16][128];

  int t = threadIdx.x;
  long m0 = (long)blockIdx.x * 64;
  int  n0 = blockIdx.y * 128;

  float acc[4][8];
#pragma unroll
  for (int i = 0; i < 4; i++)
#pragma unroll
    for (int j = 0; j < 8; j++) acc[i][j] = 0.f;

  int tm = t >> 4;
  int tn = t & 15;
  int mA  = t & 63;
  int kgA = t >> 6;

  long rowA = m0 + mA;
  bool rv = rowA < M;
  long r0 = rv ? (idx0 ? (long)idx0[rowA] : rowA) : 0;

  for (int k0 = 0; k0 < Ktot; k0 += 16){
#pragma unroll
    for (int it = 0; it < 4; it++){
      int kl = kgA + it * 4;
      int k  = k0 + kl;
      float v = 0.f;
      if (rv && k < Ktot){
        v = dt0 ? b2f(((const unsigned short*)A0)[r0 * (long)ld0 + k])
                : ((const float*)A0)[r0 * (long)ld0 + k];
        if (aScale) v = v * aScale[k] + aShift[k];
      }
      As[kl][mA] = v;
    }
#pragma unroll
    for (int it = 0; it < 8; it++){
      int idx = t + it * 256;
      int kl = idx >> 7;
      int n  = idx & 127;
      int k  = k0 + kl;
      Bs[kl][n] = (k < Ktot) ? W[(long)k * Nout + n0 + n] : 0.f;
    }
    __syncthreads();
#pragma unroll
    for (int kk = 0; kk < 16; kk++){
      float4 a  = *(const float4*)&As[kk][tm * 4];
      float4 b0 = *(const float4*)&Bs[kk][tn * 4];
      float4 b1 = *(const float4*)&Bs[kk][64 + tn * 4];
      float av[4] = {a.x, a.y, a.z, a.w};
      float bv[8] = {b0.x, b0.y, b0.z, b0.w, b1.x, b1.y, b1.z, b1.w};
#pragma unroll
      for (int i = 0; i < 4; i++)
#pragma unroll
        for (int j = 0; j < 8; j++)
          acc[i][j] = __builtin_fmaf(av[i], bv[j], acc[i][j]);
    }
    __syncthreads();
  }

#pragma unroll
  for (int i = 0; i < 4; i++){
    long m = m0 + tm * 4 + i;
    if (m >= M) continue;
#pragma unroll
    for (int h = 0; h < 2; h++){
      int nb = n0 + h * 64 + tn * 4;
      float po[4];
#pragma unroll
      for (int j = 0; j < 4; j++){
        float v = acc[i][h * 4 + j];
        if (bias) v += bias[nb + j];
        if (actMode == 1) v = v / (1.0f + __expf(-v));
        if (res) v += res[m * (long)ldRes + nb + j];
        po[j] = v;
      }
      if (outDt){
        __align__(8) unsigned short tb[4];
#pragma unroll
        for (int j = 0; j < 4; j++) tb[j] = f2b(po[j]);
        *(short4*)((bf16*)Cout + m * (long)Nout + nb) = *(short4*)tb;
      } else {
        float4 ov = {po[0], po[1], po[2], po[3]};
        *(float4*)((float*)Cout + m * (long)Nout + nb) = ov;
      }
    }
  }
}

// ---------------- utility ----------------
__global__ __launch_bounds__(256) void zero_k(float* __restrict__ p, long n){
  long i = (long)blockIdx.x * 256 + threadIdx.x;
  long stride = (long)gridDim.x * 256;
  for (; i < n; i += stride) p[i] = 0.f;
}
__global__ __launch_bounds__(256) void copy_k(float* __restrict__ d,
                                              const float* __restrict__ s, long n){
  long i = (long)blockIdx.x * 256 + threadIdx.x;
  long stride = (long)gridDim.x * 256;
  for (; i < n; i += stride) d[i] = s[i];
}

__global__ __launch_bounds__(256) void fuse_bias_k(
  const float* __restrict__ W3, const float* __restrict__ be,
  const float* __restrict__ b0, float* __restrict__ bf)
{
  int n = threadIdx.x;
  float s = b0[n];
  for (int k = 0; k < Cc; k++) s += be[k] * W3[k * Cc + n];
  bf[n] = s;
}

__global__ __launch_bounds__(256) void d_k(const float* __restrict__ ea,
                                           float* __restrict__ d, int E)
{
  int i = blockIdx.x * 256 + threadIdx.x;
  if (i < E){
    float a = ea[i * 3 + 0], b = ea[i * 3 + 1], c = ea[i * 3 + 2];
    d[i] = -rsqrtf(a * a + b * b + c * c);
  }
}

// ---------------- wave-per-row: msg *= sigmoid(LN(q[dst]*key_e*scale)) ----------------
__global__ __launch_bounds__(256) void ln_gate_w(
  bf16* __restrict__ msg, const bf16* __restrict__ keye,
  const float* __restrict__ q, const int* __restrict__ dst,
  const float* __restrict__ g, const float* __restrict__ b)
{
  int lane = threadIdx.x & 63;
  long row = (long)blockIdx.x * 4 + (threadIdx.x >> 6);
  long dr = dst[row];
  int c0 = lane * 4;
  ushort4 ks = *(const ushort4*)((const unsigned short*)keye + row * 256 + c0);
  float4  qv = *(const float4*)(q + dr * 256 + c0);
  float a0 = b2f(ks.x) * qv.x * 0.0625f;
  float a1 = b2f(ks.y) * qv.y * 0.0625f;
  float a2 = b2f(ks.z) * qv.z * 0.0625f;
  float a3 = b2f(ks.w) * qv.w * 0.0625f;
  float s1 = a0 + a1 + a2 + a3;
  float s2 = a0*a0 + a1*a1 + a2*a2 + a3*a3;
#pragma unroll
  for (int off = 1; off < 64; off <<= 1){
    s1 += __shfl_xor(s1, off, 64);
    s2 += __shfl_xor(s2, off, 64);
  }
  float m   = s1 * (1.0f / Cc);
  float var = s2 * (1.0f / Cc) - m * m;
  float rs  = rsqrtf(var + 1e-5f);
  float4 gv = *(const float4*)(g + c0);
  float4 bv = *(const float4*)(b + c0);
  ushort4 ms = *(const ushort4*)((const unsigned short*)msg + row * 256 + c0);
  float l0 = (a0 - m) * rs * gv.x + bv.x;
  float l1 = (a1 - m) * rs * gv.y + bv.y;
  float l2 = (a2 - m) * rs * gv.z + bv.z;
  float l3 = (a3 - m) * rs * gv.w + bv.w;
  ushort4 o;
  o.x = f2b(b2f(ms.x) / (1.f + __expf(-l0)));
  o.y = f2b(b2f(ms.y) / (1.f + __expf(-l1)));
  o.z = f2b(b2f(ms.z) / (1.f + __expf(-l2)));
  o.w = f2b(b2f(ms.w) / (1.f + __expf(-l3)));
  *(ushort4*)((unsigned short*)msg + row * 256 + c0) = o;
}

// ---------------- wave-per-row: agg[dst] += LN(row) ----------------
__global__ __launch_bounds__(256) void ln_scatter_w(
  const bf16* __restrict__ src, const int* __restrict__ dst,
  const float* __restrict__ g, const float* __restrict__ b,
  float* __restrict__ agg)
{
  int lane = threadIdx.x & 63;
  long row = (long)blockIdx.x * 4 + (threadIdx.x >> 6);
  int c0 = lane * 4;
  ushort4 vs = *(const ushort4*)((const unsigned short*)src + row * 256 + c0);
  float v0 = b2f(vs.x), v1 = b2f(vs.y), v2 = b2f(vs.z), v3 = b2f(vs.w);
  float s1 = v0 + v1 + v2 + v3;
  float s2 = v0*v0 + v1*v1 + v2*v2 + v3*v3;
#pragma unroll
  for (int off = 1; off < 64; off <<= 1){
    s1 += __shfl_xor(s1, off, 64);
    s2 += __shfl_xor(s2, off, 64);
  }
  float m   = s1 * (1.0f / Cc);
  float var = s2 * (1.0f / Cc) - m * m;
  float rs  = rsqrtf(var + 1e-5f);
  float4 gv = *(const float4*)(g + c0);
  float4 bv = *(const float4*)(b + c0);
  long dr = dst[row];
  float* ap = agg + dr * 256 + c0;
  atomicAdd(ap + 0, (v0 - m) * rs * gv.x + bv.x);
  atomicAdd(ap + 1, (v1 - m) * rs * gv.y + bv.y);
  atomicAdd(ap + 2, (v2 - m) * rs * gv.z + bv.z);
  atomicAdd(ap + 3, (v3 - m) * rs * gv.w + bv.w);
}

// ---------------- BatchNorm helpers ----------------
__global__ __launch_bounds__(256) void bn_stats_k(
  const float* __restrict__ X, int rows, float* __restrict__ sums)
{
  int c  = threadIdx.x;
  int r0 = blockIdx.x * 128;
  int re = r0 + 128; if (re > rows) re = rows;
  float s1 = 0.f, s2 = 0.f;
  for (int r = r0; r < re; r++){
    float v = X[(long)r * Cc + c];
    s1 += v; s2 += v * v;
  }
  atomicAdd(&sums[c],      s1);
  atomicAdd(&sums[Cc + c], s2);
}

__global__ __launch_bounds__(256) void bn_apply_softplus_k(
  float* __restrict__ x, const float* __restrict__ agg,
  const float* __restrict__ sums,
  const float* __restrict__ g, const float* __restrict__ b)
{
  long r = blockIdx.x;
  int c = threadIdx.x;
  float m    = sums[c] * (1.0f / Nn);
  float var  = sums[Cc + c] * (1.0f / Nn) - m * m;
  float rstd = rsqrtf(var + 1e-5f);
  float bn = (agg[r * Cc + c] - m) * rstd * g[c] + b[c];
  float v  = x[r * Cc + c] + bn;
  float sp = (v > 0.f) ? v + log1pf(__expf(-v)) : log1pf(__expf(v));
  x[r * Cc + c] = sp;
}

__global__ __launch_bounds__(256) void bn_st_k(
  const float* __restrict__ sums, const float* __restrict__ g,
  const float* __restrict__ b, float* __restrict__ S, float* __restrict__ T)
{
  int c = threadIdx.x;
  float m    = sums[c] * (1.0f / Nn);
  float var  = sums[Cc + c] * (1.0f / Nn) - m * m;
  float rstd = rsqrtf(var + 1e-5f);
  S[c] = g[c] * rstd;
  T[c] = b[c] - m * rstd * g[c];
}

__global__ __launch_bounds__(256) void add_k(float* __restrict__ p,
                                             const float* __restrict__ x)
{
  long i = (long)blockIdx.x * 256 + threadIdx.x;
  p[i] += x[i];
}

__global__ __launch_bounds__(256) void mulgelu_k(
  float* __restrict__ u, const float* __restrict__ x1,
  const float* __restrict__ a2)
{
  long r = blockIdx.x;
  int c = threadIdx.x;
  float xg = a2[r * 512 + 256 + c];
  float ge = 0.5f * xg * (1.0f + erff(xg * 0.70710678118654752f));
  u[r * Cc + c] = x1[r * Cc + c] * ge;
}

__global__ __launch_bounds__(256) void pool_k(
  const float* __restrict__ x, const int* __restrict__ batch,
  float* __restrict__ pooled, float* __restrict__ counts)
{
  long r = blockIdx.x;
  int c = threadIdx.x;
  long b = batch[r];
  atomicAdd(&pooled[b * Cc + c], x[r * Cc + c]);
  if (c == 0) atomicAdd(&counts[b], 1.0f);
}

__global__ __launch_bounds__(256) void pooldiv_k(
  float* __restrict__ pooled, const float* __restrict__ counts)
{
  int b = blockIdx.x;
  int c = threadIdx.x;
  float cnt = counts[b];
  if (cnt < 1.f) cnt = 1.f;
  pooled[b * Cc + c] /= cnt;
}

__global__ __launch_bounds__(256) void out_k(
  const float* __restrict__ cf, const float* __restrict__ ow,
  const float* __restrict__ ob, float* __restrict__ out)
{
  __shared__ float sm[8];
  int b = blockIdx.x;
  int c = threadIdx.x;
  float v = cf[(long)b * Cc + c] * ow[c];
  float dummy = 0.f;
  block_reduce_2(v, dummy, sm);
  if (c == 0) out[b] = v + ob[0];
}

// ---------------- host helpers ----------------
static inline void launch_gemm(hipStream_t st,
  const void* A0, const int* i0, int K0, int ld0, int dt0,
  long M, int Nout, const float* W, const float* bias,
  const float* res, int ldRes, const float* aS, const float* aT,
  void* Cout, int outDt, int act)
{
  dim3 grid((unsigned)((M + 63) / 64), (unsigned)(Nout / 128));
  gemm_k<<<grid, dim3(256), 0, st>>>(
    A0, i0, K0, ld0, dt0, M, K0, Nout, W, bias, res, ldRes, aS, aT,
    Cout, outDt, act);
}

static inline void launch_mfma(hipStream_t st,
  const bf16* A0, const int* i0, const bf16* A1, const int* i1,
  const bf16* A2, const int* i2, int nseg, long M,
  const bf16* Bpack, const float* bias, bf16* Cout, int act)
{
  mfma_gemm_k<<<dim3((unsigned)(M / 64)), dim3(256), 0, st>>>(
    A0, i0, A1, i1, A2, i2, nseg, M, Bpack, bias, Cout, act);
}

extern "C" void kernel_launch(void* const* d_in, const int* in_sizes, int n_in,
                              void* d_out, int out_size, void* d_ws, size_t ws_size,
                              hipStream_t stream)
{
  (void)in_sizes; (void)n_in; (void)out_size; (void)ws_size;

  const float* node       = (const float*)d_in[0];
  const int*   edge_index = (const int*)  d_in[1];
  const float* edge_attr  = (const float*)d_in[2];
  const float* pdd        = (const float*)d_in[3];
  const int*   batch      = (const int*)  d_in[4];
  const float* atom_W1 = (const float*)d_in[5];
  const float* atom_b1 = (const float*)d_in[6];
  const float* atom_W2 = (const float*)d_in[7];
  const float* atom_b2 = (const float*)d_in[8];
  const float* edge_W  = (const float*)d_in[9];
  const float* edge_b  = (const float*)d_in[10];
  const float* pdd_W   = (const float*)d_in[11];
  const float* pdd_b   = (const float*)d_in[12];
  const float* conv_Wq = (const float*)d_in[13];
  const float* conv_bq = (const float*)d_in[14];
  const float* conv_Wk = (const float*)d_in[15];
  const float* conv_bk = (const float*)d_in[16];
  const float* conv_Wv = (const float*)d_in[17];
  const float* conv_bv = (const float*)d_in[18];
  const float* conv_We = (const float*)d_in[19];
  const float* conv_be = (const float*)d_in[20];
  const float* conv_Wku = (const float*)d_in[21];
  const float* conv_bku = (const float*)d_in[22];
  const float* conv_Wmu = (const float*)d_in[23];
  const float* conv_bmu = (const float*)d_in[24];
  const float* conv_Wm  = (const float*)d_in[25];
  const float* conv_bm  = (const float*)d_in[26];
  const float* ln_m_g = (const float*)d_in[27];
  const float* ln_m_b = (const float*)d_in[28];
  const float* ln_a_g = (const float*)d_in[29];
  const float* ln_a_b = (const float*)d_in[30];
  const float* bn_g   = (const float*)d_in[31];
  const float* bn_b   = (const float*)d_in[32];
  const float* pddc_W1 = (const float*)d_in[33];
  const float* pddc_b1 = (const float*)d_in[34];
  const float* pddc_W2 = (const float*)d_in[35];
  const float* pddc_b2 = (const float*)d_in[36];
  const float* pddc_W3 = (const float*)d_in[37];
  const float* pddc_b3 = (const float*)d_in[38];
  const float* pddc_bn_g = (const float*)d_in[39];
  const float* pddc_bn_b = (const float*)d_in[40];
  const float* fc_W  = (const float*)d_in[41];
  const float* fc_b  = (const float*)d_in[42];
  const float* out_W = (const float*)d_in[43];
  const float* out_b = (const float*)d_in[44];

  const int* src = edge_index;
  const int* dst = edge_index + Ne;

  // ---- workspace carve-up (~240 MB) ----
  char* ws = (char*)d_ws;
  size_t off = 0;
  auto alloc = [&](size_t nbytes) -> char* {
    char* ptr = ws + off;
    off += (nbytes + 255) & ~(size_t)255;
    return ptr;
  };
  bf16*  e_in = (bf16*) alloc((size_t)Ne * Cc * 2);  // persistent
  bf16*  bufB = (bf16*) alloc((size_t)Ne * Cc * 2);  // rbf / key_e / msg2
  bf16*  bufC = (bf16*) alloc((size_t)Ne * Cc * 2);  // msg (+prep/pddc f32 scratch)
  float* x    = (float*)alloc((size_t)Nn * Cc * 4);
  float* p    = (float*)alloc((size_t)Nn * Cc * 4);
  float* q    = (float*)alloc((size_t)Nn * Cc * 4);
  float* agg  = (float*)alloc((size_t)Nn * Cc * 4);
  bf16*  kk_bf = (bf16*)alloc((size_t)Nn * Cc * 2);
  bf16*  vv_bf = (bf16*)alloc((size_t)Nn * Cc * 2);
  float* dArr  = (float*)alloc((size_t)Ne * 4);
  bf16*  WpKu  = (bf16*) alloc((size_t)3 * 768 * Cc * 2);
  bf16*  WpMu  = (bf16*) alloc((size_t)3 * 768 * Cc * 2);
  bf16*  WpM   = (bf16*) alloc((size_t)3 * Cc * Cc * 2);
  bf16*  WpE   = (bf16*) alloc((size_t)Cc * Cc * 2);
  float* bf_ku = (float*)alloc((size_t)3 * Cc * 4);
  float* bf_mu = (float*)alloc((size_t)3 * Cc * 4);
  float* pooled = (float*)alloc((size_t)Bb * Cc * 4);
  float* counts = (float*)alloc((size_t)Bb * 4);
  float* cf     = (float*)alloc((size_t)Bb * Cc * 4);
  float* bnsum  = (float*)alloc(2 * Cc * 4);
  float* bnS    = (float*)alloc(Cc * 4);
  float* bnT    = (float*)alloc(Cc * 4);

  // prep fp32 scratch aliases bufC (free until conv loop)
  float* WfKu = (float*)bufC;                 // 768x256 f32
  float* WfMu = WfKu + (size_t)768 * Cc;      // 768x256 f32
  // pddc fp32 scratch aliases edge buffers (free during pddc)
  float* a2buf = (float*)bufC;                // N x 512
  float* x1buf = (float*)bufB;                // N x 256
  float* ubuf  = x1buf + (size_t)Nn * Cc;     // N x 256

  // ---- prep: fuse We into Wku/Wmu, convert+pack all edge-GEMM weights ----
  d_k<<<dim3((Ne + 255) / 256), dim3(256), 0, stream>>>(edge_attr, dArr, Ne);

  for (int i = 0; i < 3; i++){
    const float* We_i  = conv_We  + (size_t)i * Cc * Cc;
    const float* be_i  = conv_be  + i * Cc;
    const float* Wku_i = conv_Wku + (size_t)i * 768 * Cc;
    const float* Wmu_i = conv_Wmu + (size_t)i * 768 * Cc;
    copy_k<<<dim3(512), dim3(256), 0, stream>>>(WfKu, Wku_i, (long)512 * Cc);
    copy_k<<<dim3(512), dim3(256), 0, stream>>>(WfMu, Wmu_i, (long)512 * Cc);
    launch_gemm(stream, We_i, nullptr, 256, 256, 0, 256, Cc,
                Wku_i + (size_t)512 * Cc, nullptr, nullptr, 0, nullptr, nullptr,
                WfKu + (size_t)512 * Cc, 0, 0);
    launch_gemm(stream, We_i, nullptr, 256, 256, 0, 256, Cc,
                Wmu_i + (size_t)512 * Cc, nullptr, nullptr, 0, nullptr, nullptr,
                WfMu + (size_t)512 * Cc, 0, 0);
    fuse_bias_k<<<dim3(1), dim3(256), 0, stream>>>(Wku_i + (size_t)512 * Cc, be_i,
                conv_bku + i * Cc, bf_ku + i * Cc);
    fuse_bias_k<<<dim3(1), dim3(256), 0, stream>>>(Wmu_i + (size_t)512 * Cc, be_i,
                conv_bmu + i * Cc, bf_mu + i * Cc);
    pack_b_k<<<dim3(768), dim3(256), 0, stream>>>(WfKu, WpKu + (size_t)i * 768 * Cc, 768);
    pack_b_k<<<dim3(768), dim3(256), 0, stream>>>(WfMu, WpMu + (size_t)i * 768 * Cc, 768);
    pack_b_k<<<dim3(256), dim3(256), 0, stream>>>(conv_Wm + (size_t)i * Cc * Cc,
                WpM + (size_t)i * Cc * Cc, 256);
  }
  pack_b_k<<<dim3(256), dim3(256), 0, stream>>>(edge_W, WpE, 256);

  // ---- embeddings ----
  // x = silu(node @ W1 + b1) @ W2 + b2  (hidden staged in q)
  launch_gemm(stream, node, nullptr, 92, 92, 0, Nn, Cc, atom_W1, atom_b1,
              nullptr, 0, nullptr, nullptr, q, 0, 1);
  launch_gemm(stream, q, nullptr, 256, 256, 0, Nn, Cc, atom_W2, atom_b2,
              nullptr, 0, nullptr, nullptr, x, 0, 0);
  // e_in = silu(rbf(d) @ edge_W + edge_b)  via MFMA (rbf staged bf16 in bufB)
  rbf_k<<<dim3(Ne), dim3(256), 0, stream>>>(dArr, bufB);
  launch_mfma(stream, bufB, nullptr, nullptr, nullptr, nullptr, nullptr, 1,
              Ne, WpE, edge_b, e_in, 1);
  // p = pdd @ pdd_W + pdd_b
  launch_gemm(stream, pdd, nullptr, 51, 51, 0, Nn, Cc, pdd_W, pdd_b,
              nullptr, 0, nullptr, nullptr, p, 0, 0);

  for (int i = 0; i < 3; i++){
    const float* Wq = conv_Wq + (size_t)i * Cc * Cc;
    const float* Wk = conv_Wk + (size_t)i * Cc * Cc;
    const float* Wv = conv_Wv + (size_t)i * Cc * Cc;

    launch_gemm(stream, x, nullptr, 256, 256, 0, Nn, Cc, Wq, conv_bq + i * Cc,
                nullptr, 0, nullptr, nullptr, q, 0, 0);
    launch_gemm(stream, x, nullptr, 256, 256, 0, Nn, Cc, Wk, conv_bk + i * Cc,
                nullptr, 0, nullptr, nullptr, kk_bf, 1, 0);
    launch_gemm(stream, x, nullptr, 256, 256, 0, Nn, Cc, Wv, conv_bv + i * Cc,
                nullptr, 0, nullptr, nullptr, vv_bf, 1, 0);
    // key_e = [k[dst], k[src], e_in] @ WfKu + bf_ku  -> bufB
    launch_mfma(stream, kk_bf, dst, kk_bf, src, e_in, nullptr, 3, Ne,
                WpKu + (size_t)i * 768 * Cc, bf_ku + i * Cc, bufB, 0);
    // msg = [v[dst], v[src], e_in] @ WfMu + bf_mu    -> bufC
    launch_mfma(stream, vv_bf, dst, vv_bf, src, e_in, nullptr, 3, Ne,
                WpMu + (size_t)i * 768 * Cc, bf_mu + i * Cc, bufC, 0);
    // msg *= sigmoid(LN(q[dst]*key_e*scale))
    ln_gate_w<<<dim3(Ne / 4), dim3(256), 0, stream>>>(bufC, bufB, q, dst,
                ln_a_g + i * Cc, ln_a_b + i * Cc);
    // msg2 = msg @ Wm + bm  -> bufB
    launch_mfma(stream, bufC, nullptr, nullptr, nullptr, nullptr, nullptr, 1, Ne,
                WpM + (size_t)i * Cc * Cc, conv_bm + i * Cc, bufB, 0);
    // agg = segment_sum(LN(msg2), dst)
    zero_k<<<dim3(1024), dim3(256), 0, stream>>>(agg, (long)Nn * Cc);
    ln_scatter_w<<<dim3(Ne / 4), dim3(256), 0, stream>>>(bufB, dst,
                ln_m_g + i * Cc, ln_m_b + i * Cc, agg);
    // x = softplus(x + BN(agg))
    zero_k<<<dim3(2), dim3(256), 0, stream>>>(bnsum, 2 * Cc);
    bn_stats_k<<<dim3(Nn / 128), dim3(256), 0, stream>>>(agg, Nn, bnsum);
    bn_apply_softplus_k<<<dim3(Nn), dim3(256), 0, stream>>>(x, agg, bnsum,
                bn_g + i * Cc, bn_b + i * Cc);

    if (i < 2){
      int j = i;
      add_k<<<dim3(Nn * Cc / 256), dim3(256), 0, stream>>>(p, x);
      zero_k<<<dim3(2), dim3(256), 0, stream>>>(bnsum, 2 * Cc);
      bn_stats_k<<<dim3(Nn / 128), dim3(256), 0, stream>>>(p, Nn, bnsum);
      bn_st_k<<<dim3(1), dim3(256), 0, stream>>>(bnsum,
                pddc_bn_g + j * Cc, pddc_bn_b + j * Cc, bnS, bnT);
      launch_gemm(stream, p, nullptr, 256, 256, 0, Nn, 512,
                  pddc_W1 + (size_t)j * Cc * 512, pddc_b1 + j * 512,
                  nullptr, 0, bnS, bnT, a2buf, 0, 0);
      launch_gemm(stream, a2buf, nullptr, 256, 512, 0, Nn, Cc,
                  pddc_W2 + (size_t)j * Cc * Cc, pddc_b2 + j * Cc,
                  nullptr, 0, nullptr, nullptr, x1buf, 0, 0);
      mulgelu_k<<<dim3(Nn), dim3(256), 0, stream>>>(ubuf, x1buf, a2buf);
      launch_gemm(stream, ubuf, nullptr, 256, 256, 0, Nn, Cc,
                  pddc_W3 + (size_t)j * Cc * Cc, pddc_b3 + j * Cc,
                  x, Cc, nullptr, nullptr, x, 0, 0);
    }
  }

  // ---- pooling + head ----
  zero_k<<<dim3(64), dim3(256), 0, stream>>>(pooled, (long)Bb * Cc);
  zero_k<<<dim3(1), dim3(256), 0, stream>>>(counts, Bb);
  pool_k<<<dim3(Nn), dim3(256), 0, stream>>>(x, batch, pooled, counts);
  pooldiv_k<<<dim3(Bb), dim3(256), 0, stream>>>(pooled, counts);
  launch_gemm(stream, pooled, nullptr, 256, 256, 0, Bb, Cc, fc_W, fc_b,
              pooled, Cc, nullptr, nullptr, cf, 0, 1);
  out_k<<<dim3(Bb), dim3(256), 0, stream>>>(cf, out_W, out_b, (float*)d_out);
}

// Round 4
// 3800.440 us; speedup vs baseline: 3.1758x; 1.3108x over previous
//
#include <hip/hip_runtime.h>
#include <hip/hip_bf16.h>

#define Nn 8192
#define Ne 131072
#define Cc 256
#define Bb 64

typedef __hip_bfloat16 bf16;
typedef __attribute__((ext_vector_type(8))) short bf16x8;
typedef __attribute__((ext_vector_type(4))) float f32x4;

__device__ __forceinline__ float b2f(unsigned short s){
  return __uint_as_float(((unsigned)s) << 16);
}
__device__ __forceinline__ unsigned short f2b(float v){
  bf16 h = __float2bfloat16(v);
  return *(unsigned short*)&h;
}

// ---------------- block-wide reduction (256 threads, 2 values) ----------------
__device__ __forceinline__ void block_reduce_2(float& s1, float& s2, float* sm){
#pragma unroll
  for (int off = 32; off > 0; off >>= 1){
    s1 += __shfl_down(s1, off, 64);
    s2 += __shfl_down(s2, off, 64);
  }
  int lane = threadIdx.x & 63;
  int wid  = threadIdx.x >> 6;
  if (lane == 0){ sm[wid] = s1; sm[4 + wid] = s2; }
  __syncthreads();
  s1 = sm[0] + sm[1] + sm[2] + sm[3];
  s2 = sm[4] + sm[5] + sm[6] + sm[7];
}

// ================= MFMA bf16 GEMM, N=256, K = nseg*256 =================
// BM=64, BN=256; 4 waves, each 64 rows x 64 cols, 16x16x32 mfma, fp32 acc.
// A segments: bf16, row width 256, optional row-gather idx.
// outPerm: optional output row permutation (row m stored at outPerm[m]).
// Bpack layout: element B[kc*32 + (lane>>4)*8 + j][nt*16 + (lane&15)] at
//   Bpack[((kc*16 + nt)*64 + lane)*8 + j]
__global__ __launch_bounds__(256) void mfma_gemm_k(
  const bf16* __restrict__ A0, const int* __restrict__ idx0,
  const bf16* __restrict__ A1, const int* __restrict__ idx1,
  const bf16* __restrict__ A2, const int* __restrict__ idx2,
  int nseg, long M,
  const bf16* __restrict__ Bpack, const float* __restrict__ bias,
  bf16* __restrict__ Cout, int actMode, const int* __restrict__ outPerm)
{
  int lane = threadIdx.x & 63;
  int wave = threadIdx.x >> 6;
  long m0 = (long)blockIdx.x * 64;
  int row16 = lane & 15;
  int kg    = lane >> 4;

  const bf16* Aseg[3] = {A0, A1, A2};
  const int*  Iseg[3] = {idx0, idx1, idx2};
  const bf16* abase[3][4];
  for (int s = 0; s < nseg; s++){
#pragma unroll
    for (int im = 0; im < 4; im++){
      long r = m0 + im * 16 + row16;
      long g = Iseg[s] ? (long)Iseg[s][r] : r;
      abase[s][im] = Aseg[s] + g * 256 + kg * 8;
    }
  }

  f32x4 acc[4][4];
#pragma unroll
  for (int i = 0; i < 4; i++)
#pragma unroll
    for (int j = 0; j < 4; j++) acc[i][j] = (f32x4){0.f, 0.f, 0.f, 0.f};

  int ntbase = wave * 4;
  for (int s = 0; s < nseg; s++){
    int kcbase = s * 8;
#pragma unroll
    for (int c8 = 0; c8 < 8; c8++){
      bf16x8 afrag[4], bfrag[4];
#pragma unroll
      for (int im = 0; im < 4; im++)
        afrag[im] = *(const bf16x8*)(abase[s][im] + c8 * 32);
      int kc = kcbase + c8;
#pragma unroll
      for (int in = 0; in < 4; in++){
        size_t bidx = ((size_t)(kc * 16 + ntbase + in) * 64 + lane) * 8;
        bfrag[in] = *(const bf16x8*)(Bpack + bidx);
      }
#pragma unroll
      for (int im = 0; im < 4; im++)
#pragma unroll
        for (int in = 0; in < 4; in++)
          acc[im][in] = __builtin_amdgcn_mfma_f32_16x16x32_bf16(
                          afrag[im], bfrag[in], acc[im][in], 0, 0, 0);
    }
  }

  // epilogue: C/D layout col=lane&15, row=(lane>>4)*4+reg
  int colq = lane & 15;
  int quad = lane >> 4;
#pragma unroll
  for (int im = 0; im < 4; im++){
    long orow[4];
#pragma unroll
    for (int r = 0; r < 4; r++){
      long m = m0 + im * 16 + quad * 4 + r;
      orow[r] = outPerm ? (long)outPerm[m] : m;
    }
#pragma unroll
    for (int in = 0; in < 4; in++){
      int col = wave * 64 + in * 16 + colq;
      float bv = bias ? bias[col] : 0.f;
#pragma unroll
      for (int r = 0; r < 4; r++){
        float v = acc[im][in][r] + bv;
        if (actMode == 1) v = v / (1.f + __expf(-v));
        Cout[orow[r] * 256 + col] = __float2bfloat16(v);
      }
    }
  }
}

// ---------------- pack fp32 W[K][256] -> bf16 fragment layout ----------------
__global__ __launch_bounds__(256) void pack_b_k(
  const float* __restrict__ W, bf16* __restrict__ out, int K)
{
  long p = (long)blockIdx.x * 256 + threadIdx.x;
  if (p >= (long)K * 256) return;
  int j    = p & 7;
  int lane = (p >> 3) & 63;
  int nt   = (p >> 9) & 15;
  int kc   = p >> 13;
  int k = kc * 32 + (lane >> 4) * 8 + j;
  int n = nt * 16 + (lane & 15);
  out[p] = __float2bfloat16(W[(long)k * 256 + n]);
}

// ---------------- rbf matrix (Ne x 256) bf16 ----------------
__global__ __launch_bounds__(256) void rbf_k(
  const float* __restrict__ d, bf16* __restrict__ out)
{
  long id = (long)blockIdx.x * 256 + threadIdx.x;
  long m = id >> 8;
  int  k = id & 255;
  float cen = -6.0f + (float)k * (6.0f / 255.0f);
  float df  = d[m] - cen;
  out[id] = __float2bfloat16(__expf(-42.5f * df * df));
}

// ================= generic fp32 tiled GEMM (node-sized ops) =================
__global__ __launch_bounds__(256) void gemm_k(
  const void* __restrict__ A0, const int* __restrict__ idx0, int K0, int ld0, int dt0,
  long M, int Ktot, int Nout,
  const float* __restrict__ W, const float* __restrict__ bias,
  const float* __restrict__ res, int ldRes,
  const float* __restrict__ aScale, const float* __restrict__ aShift,
  void* __restrict__ Cout, int outDt, int actMode)
{
  __shared__ __align__(16) float As[16][64];
  __shared__ __align__(16) float Bs[16][128];

  int t = threadIdx.x;
  long m0 = (long)blockIdx.x * 64;
  int  n0 = blockIdx.y * 128;

  float acc[4][8];
#pragma unroll
  for (int i = 0; i < 4; i++)
#pragma unroll
    for (int j = 0; j < 8; j++) acc[i][j] = 0.f;

  int tm = t >> 4;
  int tn = t & 15;
  int mA  = t & 63;
  int kgA = t >> 6;

  long rowA = m0 + mA;
  bool rv = rowA < M;
  long r0 = rv ? (idx0 ? (long)idx0[rowA] : rowA) : 0;

  for (int k0 = 0; k0 < Ktot; k0 += 16){
#pragma unroll
    for (int it = 0; it < 4; it++){
      int kl = kgA + it * 4;
      int k  = k0 + kl;
      float v = 0.f;
      if (rv && k < Ktot){
        v = dt0 ? b2f(((const unsigned short*)A0)[r0 * (long)ld0 + k])
                : ((const float*)A0)[r0 * (long)ld0 + k];
        if (aScale) v = v * aScale[k] + aShift[k];
      }
      As[kl][mA] = v;
    }
#pragma unroll
    for (int it = 0; it < 8; it++){
      int idx = t + it * 256;
      int kl = idx >> 7;
      int n  = idx & 127;
      int k  = k0 + kl;
      Bs[kl][n] = (k < Ktot) ? W[(long)k * Nout + n0 + n] : 0.f;
    }
    __syncthreads();
#pragma unroll
    for (int kk = 0; kk < 16; kk++){
      float4 a  = *(const float4*)&As[kk][tm * 4];
      float4 b0 = *(const float4*)&Bs[kk][tn * 4];
      float4 b1 = *(const float4*)&Bs[kk][64 + tn * 4];
      float av[4] = {a.x, a.y, a.z, a.w};
      float bv[8] = {b0.x, b0.y, b0.z, b0.w, b1.x, b1.y, b1.z, b1.w};
#pragma unroll
      for (int i = 0; i < 4; i++)
#pragma unroll
        for (int j = 0; j < 8; j++)
          acc[i][j] = __builtin_fmaf(av[i], bv[j], acc[i][j]);
    }
    __syncthreads();
  }

#pragma unroll
  for (int i = 0; i < 4; i++){
    long m = m0 + tm * 4 + i;
    if (m >= M) continue;
#pragma unroll
    for (int h = 0; h < 2; h++){
      int nb = n0 + h * 64 + tn * 4;
      float po[4];
#pragma unroll
      for (int j = 0; j < 4; j++){
        float v = acc[i][h * 4 + j];
        if (bias) v += bias[nb + j];
        if (actMode == 1) v = v / (1.0f + __expf(-v));
        if (res) v += res[m * (long)ldRes + nb + j];
        po[j] = v;
      }
      if (outDt){
        __align__(8) unsigned short tb[4];
#pragma unroll
        for (int j = 0; j < 4; j++) tb[j] = f2b(po[j]);
        *(short4*)((bf16*)Cout + m * (long)Nout + nb) = *(short4*)tb;
      } else {
        float4 ov = {po[0], po[1], po[2], po[3]};
        *(float4*)((float*)Cout + m * (long)Nout + nb) = ov;
      }
    }
  }
}

// ---------------- utility ----------------
__global__ __launch_bounds__(256) void zero_k(float* __restrict__ p, long n){
  long i = (long)blockIdx.x * 256 + threadIdx.x;
  long stride = (long)gridDim.x * 256;
  for (; i < n; i += stride) p[i] = 0.f;
}
__global__ __launch_bounds__(256) void zero_i_k(int* __restrict__ p, long n){
  long i = (long)blockIdx.x * 256 + threadIdx.x;
  long stride = (long)gridDim.x * 256;
  for (; i < n; i += stride) p[i] = 0;
}
__global__ __launch_bounds__(256) void copy_k(float* __restrict__ d,
                                              const float* __restrict__ s, long n){
  long i = (long)blockIdx.x * 256 + threadIdx.x;
  long stride = (long)gridDim.x * 256;
  for (; i < n; i += stride) d[i] = s[i];
}

__global__ __launch_bounds__(256) void fuse_bias_k(
  const float* __restrict__ W3, const float* __restrict__ be,
  const float* __restrict__ b0, float* __restrict__ bf)
{
  int n = threadIdx.x;
  float s = b0[n];
  for (int k = 0; k < Cc; k++) s += be[k] * W3[k * Cc + n];
  bf[n] = s;
}

__global__ __launch_bounds__(256) void d_k(const float* __restrict__ ea,
                                           float* __restrict__ d, int E)
{
  int i = blockIdx.x * 256 + threadIdx.x;
  if (i < E){
    float a = ea[i * 3 + 0], b = ea[i * 3 + 1], c = ea[i * 3 + 2];
    d[i] = -rsqrtf(a * a + b * b + c * c);
  }
}

// ---------------- segment sort (dst is launch-constant) ----------------
__global__ __launch_bounds__(256) void hist_k(const int* __restrict__ dst,
                                              int* __restrict__ hist)
{
  int e = blockIdx.x * 256 + threadIdx.x;
  if (e < Ne) atomicAdd(&hist[dst[e]], 1);
}

// single block, 1024 threads: exclusive scan of hist[8192] -> rowptr, counter
__global__ __launch_bounds__(1024) void scan_k(
  const int* __restrict__ hist, int* __restrict__ rowptr, int* __restrict__ counter)
{
  __shared__ int part[1024];
  int t = threadIdx.x;
  int base = t * 8;
  int local[8];
  int s = 0;
#pragma unroll
  for (int i = 0; i < 8; i++){ local[i] = s; s += hist[base + i]; }
  part[t] = s;
  __syncthreads();
  for (int off = 1; off < 1024; off <<= 1){
    int v = (t >= off) ? part[t - off] : 0;
    __syncthreads();
    part[t] += v;
    __syncthreads();
  }
  int pre = (t == 0) ? 0 : part[t - 1];
#pragma unroll
  for (int i = 0; i < 8; i++){
    int rp = pre + local[i];
    rowptr[base + i] = rp;
    counter[base + i] = rp;
  }
  if (t == 1023) rowptr[8192] = part[1023];
}

__global__ __launch_bounds__(256) void perm_k(const int* __restrict__ dst,
                                              int* __restrict__ counter,
                                              int* __restrict__ pos)
{
  int e = blockIdx.x * 256 + threadIdx.x;
  if (e < Ne) pos[e] = atomicAdd(&counter[dst[e]], 1);
}

// ---------------- wave-per-row: msg *= sigmoid(LN(q[dst]*key_e*scale)) ----------------
__global__ __launch_bounds__(256) void ln_gate_w(
  bf16* __restrict__ msg, const bf16* __restrict__ keye,
  const bf16* __restrict__ q, const int* __restrict__ dst,
  const float* __restrict__ g, const float* __restrict__ b)
{
  int lane = threadIdx.x & 63;
  long row = (long)blockIdx.x * 4 + (threadIdx.x >> 6);
  long dr = dst[row];
  int c0 = lane * 4;
  ushort4 ks = *(const ushort4*)((const unsigned short*)keye + row * 256 + c0);
  ushort4 qs = *(const ushort4*)((const unsigned short*)q + dr * 256 + c0);
  float a0 = b2f(ks.x) * b2f(qs.x) * 0.0625f;
  float a1 = b2f(ks.y) * b2f(qs.y) * 0.0625f;
  float a2 = b2f(ks.z) * b2f(qs.z) * 0.0625f;
  float a3 = b2f(ks.w) * b2f(qs.w) * 0.0625f;
  float s1 = a0 + a1 + a2 + a3;
  float s2 = a0*a0 + a1*a1 + a2*a2 + a3*a3;
#pragma unroll
  for (int off = 1; off < 64; off <<= 1){
    s1 += __shfl_xor(s1, off, 64);
    s2 += __shfl_xor(s2, off, 64);
  }
  float m   = s1 * (1.0f / Cc);
  float var = s2 * (1.0f / Cc) - m * m;
  float rs  = rsqrtf(var + 1e-5f);
  float4 gv = *(const float4*)(g + c0);
  float4 bv = *(const float4*)(b + c0);
  ushort4 ms = *(const ushort4*)((const unsigned short*)msg + row * 256 + c0);
  float l0 = (a0 - m) * rs * gv.x + bv.x;
  float l1 = (a1 - m) * rs * gv.y + bv.y;
  float l2 = (a2 - m) * rs * gv.z + bv.z;
  float l3 = (a3 - m) * rs * gv.w + bv.w;
  ushort4 o;
  o.x = f2b(b2f(ms.x) / (1.f + __expf(-l0)));
  o.y = f2b(b2f(ms.y) / (1.f + __expf(-l1)));
  o.z = f2b(b2f(ms.z) / (1.f + __expf(-l2)));
  o.w = f2b(b2f(ms.w) / (1.f + __expf(-l3)));
  *(ushort4*)((unsigned short*)msg + row * 256 + c0) = o;
}

// ---------------- wave-per-node: agg[n] = sum over dst-run of LN(row) ----------------
// msg2p rows are permuted so node n's edges occupy rows rowptr[n]..rowptr[n+1].
__global__ __launch_bounds__(256) void ln_gather_w(
  const bf16* __restrict__ msg2p, const int* __restrict__ rowptr,
  const float* __restrict__ g, const float* __restrict__ b,
  float* __restrict__ agg)
{
  int lane = threadIdx.x & 63;
  long n = (long)blockIdx.x * 4 + (threadIdx.x >> 6);
  int e0 = rowptr[n], e1 = rowptr[n + 1];
  int c0 = lane * 4;
  float t0 = 0.f, t1 = 0.f, t2 = 0.f, t3 = 0.f;
  for (int e = e0; e < e1; e++){
    ushort4 vs = *(const ushort4*)((const unsigned short*)msg2p + (long)e * 256 + c0);
    float v0 = b2f(vs.x), v1 = b2f(vs.y), v2 = b2f(vs.z), v3 = b2f(vs.w);
    float s1 = v0 + v1 + v2 + v3;
    float s2 = v0*v0 + v1*v1 + v2*v2 + v3*v3;
#pragma unroll
    for (int off = 1; off < 64; off <<= 1){
      s1 += __shfl_xor(s1, off, 64);
      s2 += __shfl_xor(s2, off, 64);
    }
    float m   = s1 * (1.0f / Cc);
    float var = s2 * (1.0f / Cc) - m * m;
    float rs  = rsqrtf(var + 1e-5f);
    t0 += (v0 - m) * rs;
    t1 += (v1 - m) * rs;
    t2 += (v2 - m) * rs;
    t3 += (v3 - m) * rs;
  }
  float cnt = (float)(e1 - e0);
  float4 gv = *(const float4*)(g + c0);
  float4 bv = *(const float4*)(b + c0);
  float4 o = { t0 * gv.x + cnt * bv.x, t1 * gv.y + cnt * bv.y,
               t2 * gv.z + cnt * bv.z, t3 * gv.w + cnt * bv.w };
  *(float4*)(agg + n * 256 + c0) = o;
}

// ---------------- BatchNorm helpers ----------------
__global__ __launch_bounds__(256) void bn_stats_k(
  const float* __restrict__ X, int rows, float* __restrict__ sums)
{
  int c  = threadIdx.x;
  int r0 = blockIdx.x * 128;
  int re = r0 + 128; if (re > rows) re = rows;
  float s1 = 0.f, s2 = 0.f;
  for (int r = r0; r < re; r++){
    float v = X[(long)r * Cc + c];
    s1 += v; s2 += v * v;
  }
  atomicAdd(&sums[c],      s1);
  atomicAdd(&sums[Cc + c], s2);
}

__global__ __launch_bounds__(256) void bn_apply_softplus_k(
  float* __restrict__ x, const float* __restrict__ agg,
  const float* __restrict__ sums,
  const float* __restrict__ g, const float* __restrict__ b)
{
  long r = blockIdx.x;
  int c = threadIdx.x;
  float m    = sums[c] * (1.0f / Nn);
  float var  = sums[Cc + c] * (1.0f / Nn) - m * m;
  float rstd = rsqrtf(var + 1e-5f);
  float bn = (agg[r * Cc + c] - m) * rstd * g[c] + b[c];
  float v  = x[r * Cc + c] + bn;
  float sp = (v > 0.f) ? v + log1pf(__expf(-v)) : log1pf(__expf(v));
  x[r * Cc + c] = sp;
}

__global__ __launch_bounds__(256) void bn_st_k(
  const float* __restrict__ sums, const float* __restrict__ g,
  const float* __restrict__ b, float* __restrict__ S, float* __restrict__ T)
{
  int c = threadIdx.x;
  float m    = sums[c] * (1.0f / Nn);
  float var  = sums[Cc + c] * (1.0f / Nn) - m * m;
  float rstd = rsqrtf(var + 1e-5f);
  S[c] = g[c] * rstd;
  T[c] = b[c] - m * rstd * g[c];
}

__global__ __launch_bounds__(256) void add_k(float* __restrict__ p,
                                             const float* __restrict__ x)
{
  long i = (long)blockIdx.x * 256 + threadIdx.x;
  p[i] += x[i];
}

__global__ __launch_bounds__(256) void mulgelu_k(
  float* __restrict__ u, const float* __restrict__ x1,
  const float* __restrict__ a2)
{
  long r = blockIdx.x;
  int c = threadIdx.x;
  float xg = a2[r * 512 + 256 + c];
  float ge = 0.5f * xg * (1.0f + erff(xg * 0.70710678118654752f));
  u[r * Cc + c] = x1[r * Cc + c] * ge;
}

__global__ __launch_bounds__(256) void pool_k(
  const float* __restrict__ x, const int* __restrict__ batch,
  float* __restrict__ pooled, float* __restrict__ counts)
{
  long r = blockIdx.x;
  int c = threadIdx.x;
  long b = batch[r];
  atomicAdd(&pooled[b * Cc + c], x[r * Cc + c]);
  if (c == 0) atomicAdd(&counts[b], 1.0f);
}

__global__ __launch_bounds__(256) void pooldiv_k(
  float* __restrict__ pooled, const float* __restrict__ counts)
{
  int b = blockIdx.x;
  int c = threadIdx.x;
  float cnt = counts[b];
  if (cnt < 1.f) cnt = 1.f;
  pooled[b * Cc + c] /= cnt;
}

__global__ __launch_bounds__(256) void out_k(
  const float* __restrict__ cf, const float* __restrict__ ow,
  const float* __restrict__ ob, float* __restrict__ out)
{
  __shared__ float sm[8];
  int b = blockIdx.x;
  int c = threadIdx.x;
  float v = cf[(long)b * Cc + c] * ow[c];
  float dummy = 0.f;
  block_reduce_2(v, dummy, sm);
  if (c == 0) out[b] = v + ob[0];
}

// ---------------- host helpers ----------------
static inline void launch_gemm(hipStream_t st,
  const void* A0, const int* i0, int K0, int ld0, int dt0,
  long M, int Nout, const float* W, const float* bias,
  const float* res, int ldRes, const float* aS, const float* aT,
  void* Cout, int outDt, int act)
{
  dim3 grid((unsigned)((M + 63) / 64), (unsigned)(Nout / 128));
  gemm_k<<<grid, dim3(256), 0, st>>>(
    A0, i0, K0, ld0, dt0, M, K0, Nout, W, bias, res, ldRes, aS, aT,
    Cout, outDt, act);
}

static inline void launch_mfma(hipStream_t st,
  const bf16* A0, const int* i0, const bf16* A1, const int* i1,
  const bf16* A2, const int* i2, int nseg, long M,
  const bf16* Bpack, const float* bias, bf16* Cout, int act,
  const int* outPerm)
{
  mfma_gemm_k<<<dim3((unsigned)(M / 64)), dim3(256), 0, st>>>(
    A0, i0, A1, i1, A2, i2, nseg, M, Bpack, bias, Cout, act, outPerm);
}

extern "C" void kernel_launch(void* const* d_in, const int* in_sizes, int n_in,
                              void* d_out, int out_size, void* d_ws, size_t ws_size,
                              hipStream_t stream)
{
  (void)in_sizes; (void)n_in; (void)out_size; (void)ws_size;

  const float* node       = (const float*)d_in[0];
  const int*   edge_index = (const int*)  d_in[1];
  const float* edge_attr  = (const float*)d_in[2];
  const float* pdd        = (const float*)d_in[3];
  const int*   batch      = (const int*)  d_in[4];
  const float* atom_W1 = (const float*)d_in[5];
  const float* atom_b1 = (const float*)d_in[6];
  const float* atom_W2 = (const float*)d_in[7];
  const float* atom_b2 = (const float*)d_in[8];
  const float* edge_W  = (const float*)d_in[9];
  const float* edge_b  = (const float*)d_in[10];
  const float* pdd_W   = (const float*)d_in[11];
  const float* pdd_b   = (const float*)d_in[12];
  const float* conv_Wq = (const float*)d_in[13];
  const float* conv_bq = (const float*)d_in[14];
  const float* conv_Wk = (const float*)d_in[15];
  const float* conv_bk = (const float*)d_in[16];
  const float* conv_Wv = (const float*)d_in[17];
  const float* conv_bv = (const float*)d_in[18];
  const float* conv_We = (const float*)d_in[19];
  const float* conv_be = (const float*)d_in[20];
  const float* conv_Wku = (const float*)d_in[21];
  const float* conv_bku = (const float*)d_in[22];
  const float* conv_Wmu = (const float*)d_in[23];
  const float* conv_bmu = (const float*)d_in[24];
  const float* conv_Wm  = (const float*)d_in[25];
  const float* conv_bm  = (const float*)d_in[26];
  const float* ln_m_g = (const float*)d_in[27];
  const float* ln_m_b = (const float*)d_in[28];
  const float* ln_a_g = (const float*)d_in[29];
  const float* ln_a_b = (const float*)d_in[30];
  const float* bn_g   = (const float*)d_in[31];
  const float* bn_b   = (const float*)d_in[32];
  const float* pddc_W1 = (const float*)d_in[33];
  const float* pddc_b1 = (const float*)d_in[34];
  const float* pddc_W2 = (const float*)d_in[35];
  const float* pddc_b2 = (const float*)d_in[36];
  const float* pddc_W3 = (const float*)d_in[37];
  const float* pddc_b3 = (const float*)d_in[38];
  const float* pddc_bn_g = (const float*)d_in[39];
  const float* pddc_bn_b = (const float*)d_in[40];
  const float* fc_W  = (const float*)d_in[41];
  const float* fc_b  = (const float*)d_in[42];
  const float* out_W = (const float*)d_in[43];
  const float* out_b = (const float*)d_in[44];

  const int* src = edge_index;
  const int* dst = edge_index + Ne;

  // ---- workspace carve-up (~250 MB) ----
  char* ws = (char*)d_ws;
  size_t off = 0;
  auto alloc = [&](size_t nbytes) -> char* {
    char* ptr = ws + off;
    off += (nbytes + 255) & ~(size_t)255;
    return ptr;
  };
  bf16*  e_in = (bf16*) alloc((size_t)Ne * Cc * 2);  // persistent
  bf16*  bufB = (bf16*) alloc((size_t)Ne * Cc * 2);  // rbf / key_e / msg2
  bf16*  bufC = (bf16*) alloc((size_t)Ne * Cc * 2);  // msg (+prep/pddc f32 scratch)
  float* x    = (float*)alloc((size_t)Nn * Cc * 4);
  float* p    = (float*)alloc((size_t)Nn * Cc * 4);
  float* hidden = (float*)alloc((size_t)Nn * Cc * 4);
  float* agg  = (float*)alloc((size_t)Nn * Cc * 4);
  bf16*  q_bf  = (bf16*)alloc((size_t)Nn * Cc * 2);
  bf16*  kk_bf = (bf16*)alloc((size_t)Nn * Cc * 2);
  bf16*  vv_bf = (bf16*)alloc((size_t)Nn * Cc * 2);
  float* dArr  = (float*)alloc((size_t)Ne * 4);
  bf16*  WpKu  = (bf16*) alloc((size_t)3 * 768 * Cc * 2);
  bf16*  WpMu  = (bf16*) alloc((size_t)3 * 768 * Cc * 2);
  bf16*  WpM   = (bf16*) alloc((size_t)3 * Cc * Cc * 2);
  bf16*  WpE   = (bf16*) alloc((size_t)Cc * Cc * 2);
  float* bf_ku = (float*)alloc((size_t)3 * Cc * 4);
  float* bf_mu = (float*)alloc((size_t)3 * Cc * 4);
  int*   hist    = (int*)alloc((size_t)8192 * 4);
  int*   rowptr  = (int*)alloc((size_t)8193 * 4);
  int*   counter = (int*)alloc((size_t)8192 * 4);
  int*   pos     = (int*)alloc((size_t)Ne * 4);
  float* pooled = (float*)alloc((size_t)Bb * Cc * 4);
  float* counts = (float*)alloc((size_t)Bb * 4);
  float* cf     = (float*)alloc((size_t)Bb * Cc * 4);
  float* bnsum  = (float*)alloc(2 * Cc * 4);
  float* bnS    = (float*)alloc(Cc * 4);
  float* bnT    = (float*)alloc(Cc * 4);

  // prep fp32 scratch aliases bufC (free until conv loop)
  float* WfKu = (float*)bufC;                 // 768x256 f32
  float* WfMu = WfKu + (size_t)768 * Cc;      // 768x256 f32
  // pddc fp32 scratch aliases edge buffers (free during pddc)
  float* a2buf = (float*)bufC;                // N x 512
  float* x1buf = (float*)bufB;                // N x 256
  float* ubuf  = x1buf + (size_t)Nn * Cc;     // N x 256

  // ---- segment structures from dst (launch-constant) ----
  zero_i_k<<<dim3(8), dim3(256), 0, stream>>>(hist, 8192);
  hist_k<<<dim3(Ne / 256), dim3(256), 0, stream>>>(dst, hist);
  scan_k<<<dim3(1), dim3(1024), 0, stream>>>(hist, rowptr, counter);
  perm_k<<<dim3(Ne / 256), dim3(256), 0, stream>>>(dst, counter, pos);

  // ---- prep: fuse We into Wku/Wmu, convert+pack all edge-GEMM weights ----
  d_k<<<dim3((Ne + 255) / 256), dim3(256), 0, stream>>>(edge_attr, dArr, Ne);

  for (int i = 0; i < 3; i++){
    const float* We_i  = conv_We  + (size_t)i * Cc * Cc;
    const float* be_i  = conv_be  + i * Cc;
    const float* Wku_i = conv_Wku + (size_t)i * 768 * Cc;
    const float* Wmu_i = conv_Wmu + (size_t)i * 768 * Cc;
    copy_k<<<dim3(512), dim3(256), 0, stream>>>(WfKu, Wku_i, (long)512 * Cc);
    copy_k<<<dim3(512), dim3(256), 0, stream>>>(WfMu, Wmu_i, (long)512 * Cc);
    launch_gemm(stream, We_i, nullptr, 256, 256, 0, 256, Cc,
                Wku_i + (size_t)512 * Cc, nullptr, nullptr, 0, nullptr, nullptr,
                WfKu + (size_t)512 * Cc, 0, 0);
    launch_gemm(stream, We_i, nullptr, 256, 256, 0, 256, Cc,
                Wmu_i + (size_t)512 * Cc, nullptr, nullptr, 0, nullptr, nullptr,
                WfMu + (size_t)512 * Cc, 0, 0);
    fuse_bias_k<<<dim3(1), dim3(256), 0, stream>>>(Wku_i + (size_t)512 * Cc, be_i,
                conv_bku + i * Cc, bf_ku + i * Cc);
    fuse_bias_k<<<dim3(1), dim3(256), 0, stream>>>(Wmu_i + (size_t)512 * Cc, be_i,
                conv_bmu + i * Cc, bf_mu + i * Cc);
    pack_b_k<<<dim3(768), dim3(256), 0, stream>>>(WfKu, WpKu + (size_t)i * 768 * Cc, 768);
    pack_b_k<<<dim3(768), dim3(256), 0, stream>>>(WfMu, WpMu + (size_t)i * 768 * Cc, 768);
    pack_b_k<<<dim3(256), dim3(256), 0, stream>>>(conv_Wm + (size_t)i * Cc * Cc,
                WpM + (size_t)i * Cc * Cc, 256);
  }
  pack_b_k<<<dim3(256), dim3(256), 0, stream>>>(edge_W, WpE, 256);

  // ---- embeddings ----
  launch_gemm(stream, node, nullptr, 92, 92, 0, Nn, Cc, atom_W1, atom_b1,
              nullptr, 0, nullptr, nullptr, hidden, 0, 1);
  launch_gemm(stream, hidden, nullptr, 256, 256, 0, Nn, Cc, atom_W2, atom_b2,
              nullptr, 0, nullptr, nullptr, x, 0, 0);
  // e_in = silu(rbf(d) @ edge_W + edge_b)  via MFMA (rbf staged bf16 in bufB)
  rbf_k<<<dim3(Ne), dim3(256), 0, stream>>>(dArr, bufB);
  launch_mfma(stream, bufB, nullptr, nullptr, nullptr, nullptr, nullptr, 1,
              Ne, WpE, edge_b, e_in, 1, nullptr);
  // p = pdd @ pdd_W + pdd_b
  launch_gemm(stream, pdd, nullptr, 51, 51, 0, Nn, Cc, pdd_W, pdd_b,
              nullptr, 0, nullptr, nullptr, p, 0, 0);

  for (int i = 0; i < 3; i++){
    const float* Wq = conv_Wq + (size_t)i * Cc * Cc;
    const float* Wk = conv_Wk + (size_t)i * Cc * Cc;
    const float* Wv = conv_Wv + (size_t)i * Cc * Cc;

    launch_gemm(stream, x, nullptr, 256, 256, 0, Nn, Cc, Wq, conv_bq + i * Cc,
                nullptr, 0, nullptr, nullptr, q_bf, 1, 0);
    launch_gemm(stream, x, nullptr, 256, 256, 0, Nn, Cc, Wk, conv_bk + i * Cc,
                nullptr, 0, nullptr, nullptr, kk_bf, 1, 0);
    launch_gemm(stream, x, nullptr, 256, 256, 0, Nn, Cc, Wv, conv_bv + i * Cc,
                nullptr, 0, nullptr, nullptr, vv_bf, 1, 0);
    // key_e = [k[dst], k[src], e_in] @ WfKu + bf_ku  -> bufB
    launch_mfma(stream, kk_bf, dst, kk_bf, src, e_in, nullptr, 3, Ne,
                WpKu + (size_t)i * 768 * Cc, bf_ku + i * Cc, bufB, 0, nullptr);
    // msg = [v[dst], v[src], e_in] @ WfMu + bf_mu    -> bufC
    launch_mfma(stream, vv_bf, dst, vv_bf, src, e_in, nullptr, 3, Ne,
                WpMu + (size_t)i * 768 * Cc, bf_mu + i * Cc, bufC, 0, nullptr);
    // msg *= sigmoid(LN(q[dst]*key_e*scale))
    ln_gate_w<<<dim3(Ne / 4), dim3(256), 0, stream>>>(bufC, bufB, q_bf, dst,
                ln_a_g + i * Cc, ln_a_b + i * Cc);
    // msg2 = msg @ Wm + bm  -> bufB, rows permuted into dst-sorted order
    launch_mfma(stream, bufC, nullptr, nullptr, nullptr, nullptr, nullptr, 1, Ne,
                WpM + (size_t)i * Cc * Cc, conv_bm + i * Cc, bufB, 0, pos);
    // agg[n] = sum of LN(msg2 rows) over node n's dst-run (no atomics)
    ln_gather_w<<<dim3(Nn / 4), dim3(256), 0, stream>>>(bufB, rowptr,
                ln_m_g + i * Cc, ln_m_b + i * Cc, agg);
    // x = softplus(x + BN(agg))
    zero_k<<<dim3(2), dim3(256), 0, stream>>>(bnsum, 2 * Cc);
    bn_stats_k<<<dim3(Nn / 128), dim3(256), 0, stream>>>(agg, Nn, bnsum);
    bn_apply_softplus_k<<<dim3(Nn), dim3(256), 0, stream>>>(x, agg, bnsum,
                bn_g + i * Cc, bn_b + i * Cc);

    if (i < 2){
      int j = i;
      add_k<<<dim3(Nn * Cc / 256), dim3(256), 0, stream>>>(p, x);
      zero_k<<<dim3(2), dim3(256), 0, stream>>>(bnsum, 2 * Cc);
      bn_stats_k<<<dim3(Nn / 128), dim3(256), 0, stream>>>(p, Nn, bnsum);
      bn_st_k<<<dim3(1), dim3(256), 0, stream>>>(bnsum,
                pddc_bn_g + j * Cc, pddc_bn_b + j * Cc, bnS, bnT);
      launch_gemm(stream, p, nullptr, 256, 256, 0, Nn, 512,
                  pddc_W1 + (size_t)j * Cc * 512, pddc_b1 + j * 512,
                  nullptr, 0, bnS, bnT, a2buf, 0, 0);
      launch_gemm(stream, a2buf, nullptr, 256, 512, 0, Nn, Cc,
                  pddc_W2 + (size_t)j * Cc * Cc, pddc_b2 + j * Cc,
                  nullptr, 0, nullptr, nullptr, x1buf, 0, 0);
      mulgelu_k<<<dim3(Nn), dim3(256), 0, stream>>>(ubuf, x1buf, a2buf);
      launch_gemm(stream, ubuf, nullptr, 256, 256, 0, Nn, Cc,
                  pddc_W3 + (size_t)j * Cc * Cc, pddc_b3 + j * Cc,
                  x, Cc, nullptr, nullptr, x, 0, 0);
    }
  }

  // ---- pooling + head ----
  zero_k<<<dim3(64), dim3(256), 0, stream>>>(pooled, (long)Bb * Cc);
  zero_k<<<dim3(1), dim3(256), 0, stream>>>(counts, Bb);
  pool_k<<<dim3(Nn), dim3(256), 0, stream>>>(x, batch, pooled, counts);
  pooldiv_k<<<dim3(Bb), dim3(256), 0, stream>>>(pooled, counts);
  launch_gemm(stream, pooled, nullptr, 256, 256, 0, Bb, Cc, fc_W, fc_b,
              pooled, Cc, nullptr, nullptr, cf, 0, 1);
  out_k<<<dim3(Bb), dim3(256), 0, stream>>>(cf, out_W, out_b, (float*)d_out);
}

// Round 5
// 3210.976 us; speedup vs baseline: 3.7588x; 1.1836x over previous
//
#include <hip/hip_runtime.h>
#include <hip/hip_bf16.h>

#define Nn 8192
#define Ne 131072
#define Cc 256
#define Bb 64

typedef __hip_bfloat16 bf16;
typedef __attribute__((ext_vector_type(8))) short bf16x8;
typedef __attribute__((ext_vector_type(4))) float f32x4;

__device__ __forceinline__ float b2f(unsigned short s){
  return __uint_as_float(((unsigned)s) << 16);
}
__device__ __forceinline__ unsigned short f2b(float v){
  bf16 h = __float2bfloat16(v);
  return *(unsigned short*)&h;
}

// ---------------- block-wide reduction (256 threads, 2 values) ----------------
__device__ __forceinline__ void block_reduce_2(float& s1, float& s2, float* sm){
#pragma unroll
  for (int off = 32; off > 0; off >>= 1){
    s1 += __shfl_down(s1, off, 64);
    s2 += __shfl_down(s2, off, 64);
  }
  int lane = threadIdx.x & 63;
  int wid  = threadIdx.x >> 6;
  if (lane == 0){ sm[wid] = s1; sm[4 + wid] = s2; }
  __syncthreads();
  s1 = sm[0] + sm[1] + sm[2] + sm[3];
  s2 = sm[4] + sm[5] + sm[6] + sm[7];
}

// ================= MFMA bf16 GEMM v2 =================
// Block: 128 rows x 256 cols; 4 waves in 2x2; wave tile 64 rows x 128 cols.
// K = NSEG*256. A segments: bf16 row-width 256, optional row gather.
// Multi-panel N via blockIdx.y: panel p uses Bpack + p*K*256, bias[p*256+col],
// writes outs[p] (row width 256). outPerm permutes output rows.
// Bpack layout: element B[kc*32 + (lane>>4)*8 + j][nt*16 + (lane&15)] at
//   ((kc*16 + nt)*64 + lane)*8 + j        (kc = k/32, nt = col/16)
template<int NSEG>
__global__ __launch_bounds__(256) void mfma2_k(
  const bf16* __restrict__ A0, const int* __restrict__ idx0,
  const bf16* __restrict__ A1, const int* __restrict__ idx1,
  const bf16* __restrict__ A2, const int* __restrict__ idx2,
  long M,
  const bf16* __restrict__ Bpack, const float* __restrict__ bias,
  bf16* __restrict__ out0, bf16* __restrict__ out1, bf16* __restrict__ out2,
  int actMode, const int* __restrict__ outPerm)
{
  int lane = threadIdx.x & 63;
  int wave = threadIdx.x >> 6;
  int wr = wave & 1;          // row half (0/1)
  int wc = wave >> 1;         // col half (0/1)
  long m0 = (long)blockIdx.x * 128;
  int panel = blockIdx.y;
  int row16 = lane & 15;
  int kg    = lane >> 4;

  const bf16* Aseg[3] = {A0, A1, A2};
  const int*  Iseg[3] = {idx0, idx1, idx2};
  const bf16* abase[NSEG][4];
#pragma unroll
  for (int s = 0; s < NSEG; s++){
#pragma unroll
    for (int im = 0; im < 4; im++){
      long r = m0 + wr * 64 + im * 16 + row16;
      long g = Iseg[s] ? (long)Iseg[s][r] : r;
      abase[s][im] = Aseg[s] + g * 256 + kg * 8;
    }
  }
  const bf16* bp = Bpack + (size_t)panel * (NSEG * 256) * 256;

  f32x4 acc[4][8];
#pragma unroll
  for (int i = 0; i < 4; i++)
#pragma unroll
    for (int j = 0; j < 8; j++) acc[i][j] = (f32x4){0.f, 0.f, 0.f, 0.f};

  int ntb = wc * 8;
#pragma unroll
  for (int s = 0; s < NSEG; s++){
#pragma unroll
    for (int c8 = 0; c8 < 8; c8++){
      int st = s * 8 + c8;
      bf16x8 a[4], b[8];
#pragma unroll
      for (int im = 0; im < 4; im++)
        a[im] = *(const bf16x8*)(abase[s][im] + c8 * 32);
#pragma unroll
      for (int in = 0; in < 8; in++)
        b[in] = *(const bf16x8*)(bp + ((size_t)(st * 16 + ntb + in) * 64 + lane) * 8);
#pragma unroll
      for (int im = 0; im < 4; im++)
#pragma unroll
        for (int in = 0; in < 8; in++)
          acc[im][in] = __builtin_amdgcn_mfma_f32_16x16x32_bf16(
                          a[im], b[in], acc[im][in], 0, 0, 0);
    }
  }

  bf16* outp = (panel == 0) ? out0 : ((panel == 1) ? out1 : out2);
  int colq = lane & 15;
  int quad = lane >> 4;
#pragma unroll
  for (int im = 0; im < 4; im++){
    long orow[4];
#pragma unroll
    for (int r = 0; r < 4; r++){
      long m = m0 + wr * 64 + im * 16 + quad * 4 + r;
      orow[r] = outPerm ? (long)outPerm[m] : m;
    }
#pragma unroll
    for (int in = 0; in < 8; in++){
      int col = wc * 128 + in * 16 + colq;
      float bv = bias ? bias[panel * 256 + col] : 0.f;
#pragma unroll
      for (int r = 0; r < 4; r++){
        float v = acc[im][in][r] + bv;
        if (actMode == 1) v = v / (1.f + __expf(-v));
        outp[orow[r] * 256 + col] = __float2bfloat16(v);
      }
    }
  }
}

// ---------------- pack fp32 W[K][256] -> bf16 fragment layout ----------------
__global__ __launch_bounds__(256) void pack_b_k(
  const float* __restrict__ W, bf16* __restrict__ out, int K)
{
  long p = (long)blockIdx.x * 256 + threadIdx.x;
  if (p >= (long)K * 256) return;
  int j    = p & 7;
  int lane = (p >> 3) & 63;
  int nt   = (p >> 9) & 15;
  int kc   = p >> 13;
  int k = kc * 32 + (lane >> 4) * 8 + j;
  int n = nt * 16 + (lane & 15);
  out[p] = __float2bfloat16(W[(long)k * 256 + n]);
}

// ---------------- rbf matrix (Ne x 256) bf16 ----------------
__global__ __launch_bounds__(256) void rbf_k(
  const float* __restrict__ d, bf16* __restrict__ out)
{
  long id = (long)blockIdx.x * 256 + threadIdx.x;
  long m = id >> 8;
  int  k = id & 255;
  float cen = -6.0f + (float)k * (6.0f / 255.0f);
  float df  = d[m] - cen;
  out[id] = __float2bfloat16(__expf(-42.5f * df * df));
}

// ================= generic fp32 tiled GEMM (node-sized / odd-K ops) =========
__global__ __launch_bounds__(256) void gemm_k(
  const void* __restrict__ A0, const int* __restrict__ idx0, int K0, int ld0, int dt0,
  long M, int Ktot, int Nout,
  const float* __restrict__ W, const float* __restrict__ bias,
  const float* __restrict__ res, int ldRes,
  const float* __restrict__ aScale, const float* __restrict__ aShift,
  void* __restrict__ Cout, int outDt, int actMode)
{
  __shared__ __align__(16) float As[16][64];
  __shared__ __align__(16) float Bs[16][128];

  int t = threadIdx.x;
  long m0 = (long)blockIdx.x * 64;
  int  n0 = blockIdx.y * 128;

  float acc[4][8];
#pragma unroll
  for (int i = 0; i < 4; i++)
#pragma unroll
    for (int j = 0; j < 8; j++) acc[i][j] = 0.f;

  int tm = t >> 4;
  int tn = t & 15;
  int mA  = t & 63;
  int kgA = t >> 6;

  long rowA = m0 + mA;
  bool rv = rowA < M;
  long r0 = rv ? (idx0 ? (long)idx0[rowA] : rowA) : 0;

  for (int k0 = 0; k0 < Ktot; k0 += 16){
#pragma unroll
    for (int it = 0; it < 4; it++){
      int kl = kgA + it * 4;
      int k  = k0 + kl;
      float v = 0.f;
      if (rv && k < Ktot){
        v = dt0 ? b2f(((const unsigned short*)A0)[r0 * (long)ld0 + k])
                : ((const float*)A0)[r0 * (long)ld0 + k];
        if (aScale) v = v * aScale[k] + aShift[k];
      }
      As[kl][mA] = v;
    }
#pragma unroll
    for (int it = 0; it < 8; it++){
      int idx = t + it * 256;
      int kl = idx >> 7;
      int n  = idx & 127;
      int k  = k0 + kl;
      Bs[kl][n] = (k < Ktot) ? W[(long)k * Nout + n0 + n] : 0.f;
    }
    __syncthreads();
#pragma unroll
    for (int kk = 0; kk < 16; kk++){
      float4 a  = *(const float4*)&As[kk][tm * 4];
      float4 b0 = *(const float4*)&Bs[kk][tn * 4];
      float4 b1 = *(const float4*)&Bs[kk][64 + tn * 4];
      float av[4] = {a.x, a.y, a.z, a.w};
      float bv[8] = {b0.x, b0.y, b0.z, b0.w, b1.x, b1.y, b1.z, b1.w};
#pragma unroll
      for (int i = 0; i < 4; i++)
#pragma unroll
        for (int j = 0; j < 8; j++)
          acc[i][j] = __builtin_fmaf(av[i], bv[j], acc[i][j]);
    }
    __syncthreads();
  }

#pragma unroll
  for (int i = 0; i < 4; i++){
    long m = m0 + tm * 4 + i;
    if (m >= M) continue;
#pragma unroll
    for (int h = 0; h < 2; h++){
      int nb = n0 + h * 64 + tn * 4;
      float po[4];
#pragma unroll
      for (int j = 0; j < 4; j++){
        float v = acc[i][h * 4 + j];
        if (bias) v += bias[nb + j];
        if (actMode == 1) v = v / (1.0f + __expf(-v));
        if (res) v += res[m * (long)ldRes + nb + j];
        po[j] = v;
      }
      if (outDt){
        __align__(8) unsigned short tb[4];
#pragma unroll
        for (int j = 0; j < 4; j++) tb[j] = f2b(po[j]);
        *(short4*)((bf16*)Cout + m * (long)Nout + nb) = *(short4*)tb;
      } else {
        float4 ov = {po[0], po[1], po[2], po[3]};
        *(float4*)((float*)Cout + m * (long)Nout + nb) = ov;
      }
    }
  }
}

// ---------------- utility ----------------
__global__ __launch_bounds__(256) void zero_k(float* __restrict__ p, long n){
  long i = (long)blockIdx.x * 256 + threadIdx.x;
  long stride = (long)gridDim.x * 256;
  for (; i < n; i += stride) p[i] = 0.f;
}
__global__ __launch_bounds__(256) void zero_i_k(int* __restrict__ p, long n){
  long i = (long)blockIdx.x * 256 + threadIdx.x;
  long stride = (long)gridDim.x * 256;
  for (; i < n; i += stride) p[i] = 0;
}
__global__ __launch_bounds__(256) void copy_k(float* __restrict__ d,
                                              const float* __restrict__ s, long n){
  long i = (long)blockIdx.x * 256 + threadIdx.x;
  long stride = (long)gridDim.x * 256;
  for (; i < n; i += stride) d[i] = s[i];
}
__global__ __launch_bounds__(256) void f2bf_k(bf16* __restrict__ d,
                                              const float* __restrict__ s, long n){
  long i = (long)blockIdx.x * 256 + threadIdx.x;
  long stride = (long)gridDim.x * 256;
  for (; i < n; i += stride) d[i] = __float2bfloat16(s[i]);
}

__global__ __launch_bounds__(256) void fuse_bias_k(
  const float* __restrict__ W3, const float* __restrict__ be,
  const float* __restrict__ b0, float* __restrict__ bf)
{
  int n = threadIdx.x;
  float s = b0[n];
  for (int k = 0; k < Cc; k++) s += be[k] * W3[k * Cc + n];
  bf[n] = s;
}

__global__ __launch_bounds__(256) void d_k(const float* __restrict__ ea,
                                           float* __restrict__ d, int E)
{
  int i = blockIdx.x * 256 + threadIdx.x;
  if (i < E){
    float a = ea[i * 3 + 0], b = ea[i * 3 + 1], c = ea[i * 3 + 2];
    d[i] = -rsqrtf(a * a + b * b + c * c);
  }
}

// ---------------- segment sort (dst is launch-constant) ----------------
__global__ __launch_bounds__(256) void hist_k(const int* __restrict__ dst,
                                              int* __restrict__ hist)
{
  int e = blockIdx.x * 256 + threadIdx.x;
  if (e < Ne) atomicAdd(&hist[dst[e]], 1);
}

__global__ __launch_bounds__(1024) void scan_k(
  const int* __restrict__ hist, int* __restrict__ rowptr, int* __restrict__ counter)
{
  __shared__ int part[1024];
  int t = threadIdx.x;
  int base = t * 8;
  int local[8];
  int s = 0;
#pragma unroll
  for (int i = 0; i < 8; i++){ local[i] = s; s += hist[base + i]; }
  part[t] = s;
  __syncthreads();
  for (int off = 1; off < 1024; off <<= 1){
    int v = (t >= off) ? part[t - off] : 0;
    __syncthreads();
    part[t] += v;
    __syncthreads();
  }
  int pre = (t == 0) ? 0 : part[t - 1];
#pragma unroll
  for (int i = 0; i < 8; i++){
    int rp = pre + local[i];
    rowptr[base + i] = rp;
    counter[base + i] = rp;
  }
  if (t == 1023) rowptr[8192] = part[1023];
}

__global__ __launch_bounds__(256) void perm_k(const int* __restrict__ dst,
                                              int* __restrict__ counter,
                                              int* __restrict__ pos)
{
  int e = blockIdx.x * 256 + threadIdx.x;
  if (e < Ne) pos[e] = atomicAdd(&counter[dst[e]], 1);
}

// ---------------- wave-per-row: msg *= sigmoid(LN(q[dst]*key_e*scale)) -------
__global__ __launch_bounds__(256) void ln_gate_w(
  bf16* __restrict__ msg, const bf16* __restrict__ keye,
  const bf16* __restrict__ q, const int* __restrict__ dst,
  const float* __restrict__ g, const float* __restrict__ b)
{
  int lane = threadIdx.x & 63;
  long row = (long)blockIdx.x * 4 + (threadIdx.x >> 6);
  long dr = dst[row];
  int c0 = lane * 4;
  ushort4 ks = *(const ushort4*)((const unsigned short*)keye + row * 256 + c0);
  ushort4 qs = *(const ushort4*)((const unsigned short*)q + dr * 256 + c0);
  float a0 = b2f(ks.x) * b2f(qs.x) * 0.0625f;
  float a1 = b2f(ks.y) * b2f(qs.y) * 0.0625f;
  float a2 = b2f(ks.z) * b2f(qs.z) * 0.0625f;
  float a3 = b2f(ks.w) * b2f(qs.w) * 0.0625f;
  float s1 = a0 + a1 + a2 + a3;
  float s2 = a0*a0 + a1*a1 + a2*a2 + a3*a3;
#pragma unroll
  for (int off = 1; off < 64; off <<= 1){
    s1 += __shfl_xor(s1, off, 64);
    s2 += __shfl_xor(s2, off, 64);
  }
  float m   = s1 * (1.0f / Cc);
  float var = s2 * (1.0f / Cc) - m * m;
  float rs  = rsqrtf(var + 1e-5f);
  float4 gv = *(const float4*)(g + c0);
  float4 bv = *(const float4*)(b + c0);
  ushort4 ms = *(const ushort4*)((const unsigned short*)msg + row * 256 + c0);
  float l0 = (a0 - m) * rs * gv.x + bv.x;
  float l1 = (a1 - m) * rs * gv.y + bv.y;
  float l2 = (a2 - m) * rs * gv.z + bv.z;
  float l3 = (a3 - m) * rs * gv.w + bv.w;
  ushort4 o;
  o.x = f2b(b2f(ms.x) / (1.f + __expf(-l0)));
  o.y = f2b(b2f(ms.y) / (1.f + __expf(-l1)));
  o.z = f2b(b2f(ms.z) / (1.f + __expf(-l2)));
  o.w = f2b(b2f(ms.w) / (1.f + __expf(-l3)));
  *(ushort4*)((unsigned short*)msg + row * 256 + c0) = o;
}

// ---------------- wave-per-node: agg[n] = sum over dst-run of LN(row) --------
__global__ __launch_bounds__(256) void ln_gather_w(
  const bf16* __restrict__ msg2p, const int* __restrict__ rowptr,
  const float* __restrict__ g, const float* __restrict__ b,
  float* __restrict__ agg)
{
  int lane = threadIdx.x & 63;
  long n = (long)blockIdx.x * 4 + (threadIdx.x >> 6);
  int e0 = rowptr[n], e1 = rowptr[n + 1];
  int c0 = lane * 4;
  float t0 = 0.f, t1 = 0.f, t2 = 0.f, t3 = 0.f;
  for (int e = e0; e < e1; e++){
    ushort4 vs = *(const ushort4*)((const unsigned short*)msg2p + (long)e * 256 + c0);
    float v0 = b2f(vs.x), v1 = b2f(vs.y), v2 = b2f(vs.z), v3 = b2f(vs.w);
    float s1 = v0 + v1 + v2 + v3;
    float s2 = v0*v0 + v1*v1 + v2*v2 + v3*v3;
#pragma unroll
    for (int off = 1; off < 64; off <<= 1){
      s1 += __shfl_xor(s1, off, 64);
      s2 += __shfl_xor(s2, off, 64);
    }
    float m   = s1 * (1.0f / Cc);
    float var = s2 * (1.0f / Cc) - m * m;
    float rs  = rsqrtf(var + 1e-5f);
    t0 += (v0 - m) * rs;
    t1 += (v1 - m) * rs;
    t2 += (v2 - m) * rs;
    t3 += (v3 - m) * rs;
  }
  float cnt = (float)(e1 - e0);
  float4 gv = *(const float4*)(g + c0);
  float4 bv = *(const float4*)(b + c0);
  float4 o = { t0 * gv.x + cnt * bv.x, t1 * gv.y + cnt * bv.y,
               t2 * gv.z + cnt * bv.z, t3 * gv.w + cnt * bv.w };
  *(float4*)(agg + n * 256 + c0) = o;
}

// ---------------- BatchNorm helpers ----------------
__global__ __launch_bounds__(256) void bn_stats_k(
  const float* __restrict__ X, int rows, float* __restrict__ sums)
{
  int c  = threadIdx.x;
  int r0 = blockIdx.x * 128;
  int re = r0 + 128; if (re > rows) re = rows;
  float s1 = 0.f, s2 = 0.f;
  for (int r = r0; r < re; r++){
    float v = X[(long)r * Cc + c];
    s1 += v; s2 += v * v;
  }
  atomicAdd(&sums[c],      s1);
  atomicAdd(&sums[Cc + c], s2);
}

__global__ __launch_bounds__(256) void bn_apply_softplus_k(
  float* __restrict__ x, const float* __restrict__ agg,
  const float* __restrict__ sums,
  const float* __restrict__ g, const float* __restrict__ b)
{
  long r = blockIdx.x;
  int c = threadIdx.x;
  float m    = sums[c] * (1.0f / Nn);
  float var  = sums[Cc + c] * (1.0f / Nn) - m * m;
  float rstd = rsqrtf(var + 1e-5f);
  float bn = (agg[r * Cc + c] - m) * rstd * g[c] + b[c];
  float v  = x[r * Cc + c] + bn;
  float sp = (v > 0.f) ? v + log1pf(__expf(-v)) : log1pf(__expf(v));
  x[r * Cc + c] = sp;
}

__global__ __launch_bounds__(256) void bn_st_k(
  const float* __restrict__ sums, const float* __restrict__ g,
  const float* __restrict__ b, float* __restrict__ S, float* __restrict__ T)
{
  int c = threadIdx.x;
  float m    = sums[c] * (1.0f / Nn);
  float var  = sums[Cc + c] * (1.0f / Nn) - m * m;
  float rstd = rsqrtf(var + 1e-5f);
  S[c] = g[c] * rstd;
  T[c] = b[c] - m * rstd * g[c];
}

__global__ __launch_bounds__(256) void add_k(float* __restrict__ p,
                                             const float* __restrict__ x)
{
  long i = (long)blockIdx.x * 256 + threadIdx.x;
  p[i] += x[i];
}

__global__ __launch_bounds__(256) void mulgelu_k(
  float* __restrict__ u, const float* __restrict__ x1,
  const float* __restrict__ a2)
{
  long r = blockIdx.x;
  int c = threadIdx.x;
  float xg = a2[r * 512 + 256 + c];
  float ge = 0.5f * xg * (1.0f + erff(xg * 0.70710678118654752f));
  u[r * Cc + c] = x1[r * Cc + c] * ge;
}

__global__ __launch_bounds__(256) void pool_k(
  const float* __restrict__ x, const int* __restrict__ batch,
  float* __restrict__ pooled, float* __restrict__ counts)
{
  long r = blockIdx.x;
  int c = threadIdx.x;
  long b = batch[r];
  atomicAdd(&pooled[b * Cc + c], x[r * Cc + c]);
  if (c == 0) atomicAdd(&counts[b], 1.0f);
}

__global__ __launch_bounds__(256) void pooldiv_k(
  float* __restrict__ pooled, const float* __restrict__ counts)
{
  int b = blockIdx.x;
  int c = threadIdx.x;
  float cnt = counts[b];
  if (cnt < 1.f) cnt = 1.f;
  pooled[b * Cc + c] /= cnt;
}

__global__ __launch_bounds__(256) void out_k(
  const float* __restrict__ cf, const float* __restrict__ ow,
  const float* __restrict__ ob, float* __restrict__ out)
{
  __shared__ float sm[8];
  int b = blockIdx.x;
  int c = threadIdx.x;
  float v = cf[(long)b * Cc + c] * ow[c];
  float dummy = 0.f;
  block_reduce_2(v, dummy, sm);
  if (c == 0) out[b] = v + ob[0];
}

// ---------------- host helpers ----------------
static inline void launch_gemm(hipStream_t st,
  const void* A0, const int* i0, int K0, int ld0, int dt0,
  long M, int Nout, const float* W, const float* bias,
  const float* res, int ldRes, const float* aS, const float* aT,
  void* Cout, int outDt, int act)
{
  dim3 grid((unsigned)((M + 63) / 64), (unsigned)(Nout / 128));
  gemm_k<<<grid, dim3(256), 0, st>>>(
    A0, i0, K0, ld0, dt0, M, K0, Nout, W, bias, res, ldRes, aS, aT,
    Cout, outDt, act);
}

static inline void launch_mfma(hipStream_t st, int nseg,
  const bf16* A0, const int* i0, const bf16* A1, const int* i1,
  const bf16* A2, const int* i2, long M, int panels,
  const bf16* Bpack, const float* bias,
  bf16* o0, bf16* o1, bf16* o2, int act, const int* outPerm)
{
  dim3 grid((unsigned)(M / 128), (unsigned)panels);
  if (nseg == 3)
    mfma2_k<3><<<grid, dim3(256), 0, st>>>(A0, i0, A1, i1, A2, i2, M,
      Bpack, bias, o0, o1, o2, act, outPerm);
  else
    mfma2_k<1><<<grid, dim3(256), 0, st>>>(A0, i0, A1, i1, A2, i2, M,
      Bpack, bias, o0, o1, o2, act, outPerm);
}

extern "C" void kernel_launch(void* const* d_in, const int* in_sizes, int n_in,
                              void* d_out, int out_size, void* d_ws, size_t ws_size,
                              hipStream_t stream)
{
  (void)in_sizes; (void)n_in; (void)out_size; (void)ws_size;

  const float* node       = (const float*)d_in[0];
  const int*   edge_index = (const int*)  d_in[1];
  const float* edge_attr  = (const float*)d_in[2];
  const float* pdd        = (const float*)d_in[3];
  const int*   batch      = (const int*)  d_in[4];
  const float* atom_W1 = (const float*)d_in[5];
  const float* atom_b1 = (const float*)d_in[6];
  const float* atom_W2 = (const float*)d_in[7];
  const float* atom_b2 = (const float*)d_in[8];
  const float* edge_W  = (const float*)d_in[9];
  const float* edge_b  = (const float*)d_in[10];
  const float* pdd_W   = (const float*)d_in[11];
  const float* pdd_b   = (const float*)d_in[12];
  const float* conv_Wq = (const float*)d_in[13];
  const float* conv_bq = (const float*)d_in[14];
  const float* conv_Wk = (const float*)d_in[15];
  const float* conv_bk = (const float*)d_in[16];
  const float* conv_Wv = (const float*)d_in[17];
  const float* conv_bv = (const float*)d_in[18];
  const float* conv_We = (const float*)d_in[19];
  const float* conv_be = (const float*)d_in[20];
  const float* conv_Wku = (const float*)d_in[21];
  const float* conv_bku = (const float*)d_in[22];
  const float* conv_Wmu = (const float*)d_in[23];
  const float* conv_bmu = (const float*)d_in[24];
  const float* conv_Wm  = (const float*)d_in[25];
  const float* conv_bm  = (const float*)d_in[26];
  const float* ln_m_g = (const float*)d_in[27];
  const float* ln_m_b = (const float*)d_in[28];
  const float* ln_a_g = (const float*)d_in[29];
  const float* ln_a_b = (const float*)d_in[30];
  const float* bn_g   = (const float*)d_in[31];
  const float* bn_b   = (const float*)d_in[32];
  const float* pddc_W1 = (const float*)d_in[33];
  const float* pddc_b1 = (const float*)d_in[34];
  const float* pddc_W2 = (const float*)d_in[35];
  const float* pddc_b2 = (const float*)d_in[36];
  const float* pddc_W3 = (const float*)d_in[37];
  const float* pddc_b3 = (const float*)d_in[38];
  const float* pddc_bn_g = (const float*)d_in[39];
  const float* pddc_bn_b = (const float*)d_in[40];
  const float* fc_W  = (const float*)d_in[41];
  const float* fc_b  = (const float*)d_in[42];
  const float* out_W = (const float*)d_in[43];
  const float* out_b = (const float*)d_in[44];

  const int* src = edge_index;
  const int* dst = edge_index + Ne;

  // ---- workspace carve-up (~260 MB) ----
  char* ws = (char*)d_ws;
  size_t off = 0;
  auto alloc = [&](size_t nbytes) -> char* {
    char* ptr = ws + off;
    off += (nbytes + 255) & ~(size_t)255;
    return ptr;
  };
  bf16*  e_in = (bf16*) alloc((size_t)Ne * Cc * 2);  // persistent
  bf16*  bufB = (bf16*) alloc((size_t)Ne * Cc * 2);  // rbf / key_e / msg2
  bf16*  bufC = (bf16*) alloc((size_t)Ne * Cc * 2);  // msg (+prep/pddc f32 scratch)
  float* x    = (float*)alloc((size_t)Nn * Cc * 4);
  float* p    = (float*)alloc((size_t)Nn * Cc * 4);
  float* hidden = (float*)alloc((size_t)Nn * Cc * 4);
  float* agg  = (float*)alloc((size_t)Nn * Cc * 4);
  bf16*  x_bf  = (bf16*)alloc((size_t)Nn * Cc * 2);
  bf16*  q_bf  = (bf16*)alloc((size_t)Nn * Cc * 2);
  bf16*  kk_bf = (bf16*)alloc((size_t)Nn * Cc * 2);
  bf16*  vv_bf = (bf16*)alloc((size_t)Nn * Cc * 2);
  float* dArr  = (float*)alloc((size_t)Ne * 4);
  bf16*  WpKu  = (bf16*) alloc((size_t)3 * 768 * Cc * 2);
  bf16*  WpMu  = (bf16*) alloc((size_t)3 * 768 * Cc * 2);
  bf16*  WpM   = (bf16*) alloc((size_t)3 * Cc * Cc * 2);
  bf16*  WpQKV = (bf16*) alloc((size_t)9 * Cc * Cc * 2);
  bf16*  WpE   = (bf16*) alloc((size_t)Cc * Cc * 2);
  float* qkvb  = (float*)alloc((size_t)3 * 768 * 4);
  float* bf_ku = (float*)alloc((size_t)3 * Cc * 4);
  float* bf_mu = (float*)alloc((size_t)3 * Cc * 4);
  int*   hist    = (int*)alloc((size_t)8192 * 4);
  int*   rowptr  = (int*)alloc((size_t)8193 * 4);
  int*   counter = (int*)alloc((size_t)8192 * 4);
  int*   pos     = (int*)alloc((size_t)Ne * 4);
  float* pooled = (float*)alloc((size_t)Bb * Cc * 4);
  float* counts = (float*)alloc((size_t)Bb * 4);
  float* cf     = (float*)alloc((size_t)Bb * Cc * 4);
  float* bnsum  = (float*)alloc(2 * Cc * 4);
  float* bnS    = (float*)alloc(Cc * 4);
  float* bnT    = (float*)alloc(Cc * 4);

  // prep fp32 scratch aliases bufC (free until conv loop)
  float* WfKu = (float*)bufC;                 // 768x256 f32
  float* WfMu = WfKu + (size_t)768 * Cc;      // 768x256 f32
  // pddc fp32 scratch aliases edge buffers (free during pddc)
  float* a2buf = (float*)bufC;                // N x 512
  float* x1buf = (float*)bufB;                // N x 256
  float* ubuf  = x1buf + (size_t)Nn * Cc;     // N x 256

  // ---- segment structures from dst (launch-constant) ----
  zero_i_k<<<dim3(8), dim3(256), 0, stream>>>(hist, 8192);
  hist_k<<<dim3(Ne / 256), dim3(256), 0, stream>>>(dst, hist);
  scan_k<<<dim3(1), dim3(1024), 0, stream>>>(hist, rowptr, counter);
  perm_k<<<dim3(Ne / 256), dim3(256), 0, stream>>>(dst, counter, pos);

  // ---- prep: fuse We into Wku/Wmu, convert+pack all MFMA weights ----
  d_k<<<dim3((Ne + 255) / 256), dim3(256), 0, stream>>>(edge_attr, dArr, Ne);

  for (int i = 0; i < 3; i++){
    const float* We_i  = conv_We  + (size_t)i * Cc * Cc;
    const float* be_i  = conv_be  + i * Cc;
    const float* Wku_i = conv_Wku + (size_t)i * 768 * Cc;
    const float* Wmu_i = conv_Wmu + (size_t)i * 768 * Cc;
    copy_k<<<dim3(512), dim3(256), 0, stream>>>(WfKu, Wku_i, (long)512 * Cc);
    copy_k<<<dim3(512), dim3(256), 0, stream>>>(WfMu, Wmu_i, (long)512 * Cc);
    launch_gemm(stream, We_i, nullptr, 256, 256, 0, 256, Cc,
                Wku_i + (size_t)512 * Cc, nullptr, nullptr, 0, nullptr, nullptr,
                WfKu + (size_t)512 * Cc, 0, 0);
    launch_gemm(stream, We_i, nullptr, 256, 256, 0, 256, Cc,
                Wmu_i + (size_t)512 * Cc, nullptr, nullptr, 0, nullptr, nullptr,
                WfMu + (size_t)512 * Cc, 0, 0);
    fuse_bias_k<<<dim3(1), dim3(256), 0, stream>>>(Wku_i + (size_t)512 * Cc, be_i,
                conv_bku + i * Cc, bf_ku + i * Cc);
    fuse_bias_k<<<dim3(1), dim3(256), 0, stream>>>(Wmu_i + (size_t)512 * Cc, be_i,
                conv_bmu + i * Cc, bf_mu + i * Cc);
    pack_b_k<<<dim3(768), dim3(256), 0, stream>>>(WfKu, WpKu + (size_t)i * 768 * Cc, 768);
    pack_b_k<<<dim3(768), dim3(256), 0, stream>>>(WfMu, WpMu + (size_t)i * 768 * Cc, 768);
    pack_b_k<<<dim3(256), dim3(256), 0, stream>>>(conv_Wm + (size_t)i * Cc * Cc,
                WpM + (size_t)i * Cc * Cc, 256);
    // qkv weights packed per panel, bias assembled contiguously
    pack_b_k<<<dim3(256), dim3(256), 0, stream>>>(conv_Wq + (size_t)i * Cc * Cc,
                WpQKV + (size_t)(i * 3 + 0) * Cc * Cc, 256);
    pack_b_k<<<dim3(256), dim3(256), 0, stream>>>(conv_Wk + (size_t)i * Cc * Cc,
                WpQKV + (size_t)(i * 3 + 1) * Cc * Cc, 256);
    pack_b_k<<<dim3(256), dim3(256), 0, stream>>>(conv_Wv + (size_t)i * Cc * Cc,
                WpQKV + (size_t)(i * 3 + 2) * Cc * Cc, 256);
    copy_k<<<dim3(1), dim3(256), 0, stream>>>(qkvb + i * 768,       conv_bq + i * Cc, Cc);
    copy_k<<<dim3(1), dim3(256), 0, stream>>>(qkvb + i * 768 + 256, conv_bk + i * Cc, Cc);
    copy_k<<<dim3(1), dim3(256), 0, stream>>>(qkvb + i * 768 + 512, conv_bv + i * Cc, Cc);
  }
  pack_b_k<<<dim3(256), dim3(256), 0, stream>>>(edge_W, WpE, 256);

  // ---- embeddings ----
  launch_gemm(stream, node, nullptr, 92, 92, 0, Nn, Cc, atom_W1, atom_b1,
              nullptr, 0, nullptr, nullptr, hidden, 0, 1);
  launch_gemm(stream, hidden, nullptr, 256, 256, 0, Nn, Cc, atom_W2, atom_b2,
              nullptr, 0, nullptr, nullptr, x, 0, 0);
  // e_in = silu(rbf(d) @ edge_W + edge_b)  via MFMA (rbf staged bf16 in bufB)
  rbf_k<<<dim3(Ne), dim3(256), 0, stream>>>(dArr, bufB);
  launch_mfma(stream, 1, bufB, nullptr, nullptr, nullptr, nullptr, nullptr,
              Ne, 1, WpE, edge_b, e_in, nullptr, nullptr, 1, nullptr);
  // p = pdd @ pdd_W + pdd_b
  launch_gemm(stream, pdd, nullptr, 51, 51, 0, Nn, Cc, pdd_W, pdd_b,
              nullptr, 0, nullptr, nullptr, p, 0, 0);

  for (int i = 0; i < 3; i++){
    // q,k,v = x_bf @ [Wq|Wk|Wv] + b  (one 3-panel MFMA dispatch)
    f2bf_k<<<dim3(512), dim3(256), 0, stream>>>(x_bf, x, (long)Nn * Cc);
    launch_mfma(stream, 1, x_bf, nullptr, nullptr, nullptr, nullptr, nullptr,
                Nn, 3, WpQKV + (size_t)i * 3 * Cc * Cc, qkvb + i * 768,
                q_bf, kk_bf, vv_bf, 0, nullptr);
    // key_e = [k[dst], k[src], e_in] @ WfKu + bf_ku  -> bufB
    launch_mfma(stream, 3, kk_bf, dst, kk_bf, src, e_in, nullptr, Ne, 1,
                WpKu + (size_t)i * 768 * Cc, bf_ku + i * Cc,
                bufB, nullptr, nullptr, 0, nullptr);
    // msg = [v[dst], v[src], e_in] @ WfMu + bf_mu    -> bufC
    launch_mfma(stream, 3, vv_bf, dst, vv_bf, src, e_in, nullptr, Ne, 1,
                WpMu + (size_t)i * 768 * Cc, bf_mu + i * Cc,
                bufC, nullptr, nullptr, 0, nullptr);
    // msg *= sigmoid(LN(q[dst]*key_e*scale))
    ln_gate_w<<<dim3(Ne / 4), dim3(256), 0, stream>>>(bufC, bufB, q_bf, dst,
                ln_a_g + i * Cc, ln_a_b + i * Cc);
    // msg2 = msg @ Wm + bm  -> bufB, rows permuted into dst-sorted order
    launch_mfma(stream, 1, bufC, nullptr, nullptr, nullptr, nullptr, nullptr, Ne, 1,
                WpM + (size_t)i * Cc * Cc, conv_bm + i * Cc,
                bufB, nullptr, nullptr, 0, pos);
    // agg[n] = sum of LN(msg2 rows) over node n's dst-run (no atomics)
    ln_gather_w<<<dim3(Nn / 4), dim3(256), 0, stream>>>(bufB, rowptr,
                ln_m_g + i * Cc, ln_m_b + i * Cc, agg);
    // x = softplus(x + BN(agg))
    zero_k<<<dim3(2), dim3(256), 0, stream>>>(bnsum, 2 * Cc);
    bn_stats_k<<<dim3(Nn / 128), dim3(256), 0, stream>>>(agg, Nn, bnsum);
    bn_apply_softplus_k<<<dim3(Nn), dim3(256), 0, stream>>>(x, agg, bnsum,
                bn_g + i * Cc, bn_b + i * Cc);

    if (i < 2){
      int j = i;
      add_k<<<dim3(Nn * Cc / 256), dim3(256), 0, stream>>>(p, x);
      zero_k<<<dim3(2), dim3(256), 0, stream>>>(bnsum, 2 * Cc);
      bn_stats_k<<<dim3(Nn / 128), dim3(256), 0, stream>>>(p, Nn, bnsum);
      bn_st_k<<<dim3(1), dim3(256), 0, stream>>>(bnsum,
                pddc_bn_g + j * Cc, pddc_bn_b + j * Cc, bnS, bnT);
      launch_gemm(stream, p, nullptr, 256, 256, 0, Nn, 512,
                  pddc_W1 + (size_t)j * Cc * 512, pddc_b1 + j * 512,
                  nullptr, 0, bnS, bnT, a2buf, 0, 0);
      launch_gemm(stream, a2buf, nullptr, 256, 512, 0, Nn, Cc,
                  pddc_W2 + (size_t)j * Cc * Cc, pddc_b2 + j * Cc,
                  nullptr, 0, nullptr, nullptr, x1buf, 0, 0);
      mulgelu_k<<<dim3(Nn), dim3(256), 0, stream>>>(ubuf, x1buf, a2buf);
      launch_gemm(stream, ubuf, nullptr, 256, 256, 0, Nn, Cc,
                  pddc_W3 + (size_t)j * Cc * Cc, pddc_b3 + j * Cc,
                  x, Cc, nullptr, nullptr, x, 0, 0);
    }
  }

  // ---- pooling + head ----
  zero_k<<<dim3(64), dim3(256), 0, stream>>>(pooled, (long)Bb * Cc);
  zero_k<<<dim3(1), dim3(256), 0, stream>>>(counts, Bb);
  pool_k<<<dim3(Nn), dim3(256), 0, stream>>>(x, batch, pooled, counts);
  pooldiv_k<<<dim3(Bb), dim3(256), 0, stream>>>(pooled, counts);
  launch_gemm(stream, pooled, nullptr, 256, 256, 0, Bb, Cc, fc_W, fc_b,
              pooled, Cc, nullptr, nullptr, cf, 0, 1);
  out_k<<<dim3(Bb), dim3(256), 0, stream>>>(cf, out_W, out_b, (float*)d_out);
}